// Round 1
// baseline (5855.685 us; speedup 1.0000x reference)
//
#include <hip/hip_runtime.h>
#include <math.h>

// ---- problem dims ----
#define Bq    2
#define Tq    16
#define IHq   224
#define IWq   224
#define Cq    3
#define TPq   4
#define PSq   16
#define Dq    512
#define DFFq  2048
#define Lq    6
#define NHq   8
#define HDq   64
#define Kq    8192
#define Tpq   4
#define Hpq   14
#define Wpq   14
#define Sq    784
#define PINq  3072
#define TOKq  1568            // B*S
#define RECN  4816896L        // B*T*IH*IW*C

// ---- workspace layout (float offsets) ----
#define OFF_BIG  0L
#define SZ_BIG   12845056L            // max(d2 [1568*8192], att [16*784*784], patches/px [1568*3072])
#define OFF_Z    (OFF_BIG + SZ_BIG)
#define OFF_XLN  (OFF_Z    + 802816L)
#define OFF_QKV  (OFF_XLN  + 802816L)
#define OFF_ATTO (OFF_QKV  + 2408448L)
#define OFF_H    (OFF_ATTO + 802816L)
#define OFF_ZE   (OFF_H    + 3211264L)
#define OFF_ZQ   (OFF_ZE   + 802816L)
#define OFF_CN   (OFF_ZQ   + 802816L)
#define OFF_IDX  (OFF_CN   + 8192L)   // int
#define OFF_CNT  (OFF_IDX  + 1568L)
#define OFF_PART (OFF_CNT  + 8192L)
#define OFF_END  (OFF_PART + 1568L)

// ================= wave reductions =================
__device__ __forceinline__ float wave_sum(float v) {
    #pragma unroll
    for (int o = 32; o; o >>= 1) v += __shfl_xor(v, o);
    return v;
}
__device__ __forceinline__ float wave_max(float v) {
    #pragma unroll
    for (int o = 32; o; o >>= 1) v = fmaxf(v, __shfl_xor(v, o));
    return v;
}
__device__ __forceinline__ float gelu_f(float x) {
    float x3 = x * x * x;
    return 0.5f * x * (1.0f + tanhf(0.7978845608028654f * (x + 0.044715f * x3)));
}

// ================= generic tiled f32 GEMM =================
// C[m,n] = epi( sum_k A[m,k]*B[k,n] )   (TRB: B stored [N,K] row-major, i.e. C = A @ Bt^T)
// EPI 0: alpha*acc + bias[n] (bias optional)
// EPI 1: C[m,n] + acc + bias[n]      (residual in-place)
// EPI 2: gelu(acc + bias[n])
// EPI 3: extra[n] - 2*acc            (VQ distances, row-constant |z|^2 dropped)
template<int EPI, bool TRB>
__global__ __launch_bounds__(256)
void gemm_f32(const float* __restrict__ A, int lda,
              const float* __restrict__ B, int ldb,
              const float* __restrict__ bias,
              const float* __restrict__ extra,
              float* __restrict__ C, int ldc,
              int M, int N, int K, float alpha, int bdiv,
              long soA, long siA, long soB, long siB,
              long soC, long siC, long soBias, long siBias)
{
    __shared__ float As[16][68];
    __shared__ float Bs[16][68];
    const int zb = blockIdx.z;
    const int zo = zb / bdiv, zi = zb - zo * bdiv;
    A += zo * soA + zi * siA;
    B += zo * soB + zi * siB;
    C += zo * soC + zi * siC;
    if (bias) bias += zo * soBias + zi * siBias;

    const int t = threadIdx.x;
    const int m0 = blockIdx.x << 6, n0 = blockIdx.y << 6;
    const int ty = t >> 4, tx = t & 15;
    const int ar = t >> 2, ac4 = (t & 3) << 2;   // A tile: 64 rows x 16 k
    const int br = t >> 4, bc4 = (t & 15) << 2;  // B tile (non-TRB): 16 k x 64 cols

    float acc[4][4] = {};

    for (int k0 = 0; k0 < K; k0 += 16) {
        // --- A tile ---
        {
            float4 va = make_float4(0.f, 0.f, 0.f, 0.f);
            int gr = m0 + ar;
            if (gr < M) va = *(const float4*)(A + (long)gr * lda + (k0 + ac4));
            As[ac4 + 0][ar] = va.x; As[ac4 + 1][ar] = va.y;
            As[ac4 + 2][ar] = va.z; As[ac4 + 3][ar] = va.w;
        }
        // --- B tile ---
        if (!TRB) {
            float4 vb = make_float4(0.f, 0.f, 0.f, 0.f);
            int gc = n0 + bc4;
            if (gc < N) vb = *(const float4*)(B + (long)(k0 + br) * ldb + gc);
            *(float4*)&Bs[br][bc4] = vb;
        } else {
            float4 vb = make_float4(0.f, 0.f, 0.f, 0.f);
            int gn = n0 + ar;
            if (gn < N) vb = *(const float4*)(B + (long)gn * ldb + (k0 + ac4));
            Bs[ac4 + 0][ar] = vb.x; Bs[ac4 + 1][ar] = vb.y;
            Bs[ac4 + 2][ar] = vb.z; Bs[ac4 + 3][ar] = vb.w;
        }
        __syncthreads();
        #pragma unroll
        for (int kk = 0; kk < 16; ++kk) {
            float a0[4], b0[4];
            *(float4*)a0 = *(const float4*)&As[kk][ty << 2];
            *(float4*)b0 = *(const float4*)&Bs[kk][tx << 2];
            #pragma unroll
            for (int i = 0; i < 4; ++i)
                #pragma unroll
                for (int j = 0; j < 4; ++j)
                    acc[i][j] = fmaf(a0[i], b0[j], acc[i][j]);
        }
        __syncthreads();
    }

    const int gn0 = n0 + (tx << 2);
    if (gn0 >= N) return;                 // N % 4 == 0 -> quad all-or-nothing
    #pragma unroll
    for (int i = 0; i < 4; ++i) {
        int gm = m0 + (ty << 2) + i;
        if (gm >= M) return;              // rows increase with i
        float* cp = C + (long)gm * ldc + gn0;
        float vj[4];
        #pragma unroll
        for (int j = 0; j < 4; ++j) {
            float v = acc[i][j];
            if (EPI == 0)      v = alpha * v + (bias ? bias[gn0 + j] : 0.0f);
            else if (EPI == 1) v = cp[j] + v + bias[gn0 + j];
            else if (EPI == 2) v = gelu_f(v + bias[gn0 + j]);
            else               v = extra[gn0 + j] - 2.0f * v;
            vj[j] = v;
        }
        float4 o; o.x = vj[0]; o.y = vj[1]; o.z = vj[2]; o.w = vj[3];
        *(float4*)cp = o;
    }
}

// ================= LayerNorm: wave per row (D=512) =================
__global__ __launch_bounds__(256)
void ln_kernel(const float* __restrict__ x, const float* __restrict__ s,
               const float* __restrict__ b, float* __restrict__ y, int rows)
{
    int wave = threadIdx.x >> 6, lane = threadIdx.x & 63;
    int row = (blockIdx.x << 2) + wave;
    if (row >= rows) return;
    const float* xr = x + (long)row * Dq;
    float4 v0 = *(const float4*)(xr + (lane << 2));
    float4 v1 = *(const float4*)(xr + 256 + (lane << 2));
    float sum = v0.x + v0.y + v0.z + v0.w + v1.x + v1.y + v1.z + v1.w;
    sum = wave_sum(sum);
    float m = sum * (1.0f / 512.0f);
    float d0x = v0.x - m, d0y = v0.y - m, d0z = v0.z - m, d0w = v0.w - m;
    float d1x = v1.x - m, d1y = v1.y - m, d1z = v1.z - m, d1w = v1.w - m;
    float vs = d0x*d0x + d0y*d0y + d0z*d0z + d0w*d0w + d1x*d1x + d1y*d1y + d1z*d1z + d1w*d1w;
    vs = wave_sum(vs);
    float rstd = 1.0f / sqrtf(vs * (1.0f / 512.0f) + 1e-6f);
    float* yr = y + (long)row * Dq;
    int c0 = lane << 2;
    float4 o0, o1;
    o0.x = d0x * rstd * s[c0+0] + b[c0+0];
    o0.y = d0y * rstd * s[c0+1] + b[c0+1];
    o0.z = d0z * rstd * s[c0+2] + b[c0+2];
    o0.w = d0w * rstd * s[c0+3] + b[c0+3];
    o1.x = d1x * rstd * s[256+c0+0] + b[256+c0+0];
    o1.y = d1y * rstd * s[256+c0+1] + b[256+c0+1];
    o1.z = d1z * rstd * s[256+c0+2] + b[256+c0+2];
    o1.w = d1w * rstd * s[256+c0+3] + b[256+c0+3];
    *(float4*)(yr + c0) = o0;
    *(float4*)(yr + 256 + c0) = o1;
}

// ================= softmax: wave per row (n=784) =================
__global__ __launch_bounds__(256)
void softmax_kernel(float* __restrict__ att, int rows, int n)
{
    int wave = threadIdx.x >> 6, lane = threadIdx.x & 63;
    int row = (blockIdx.x << 2) + wave;
    if (row >= rows) return;
    float* a = att + (long)row * n;
    float e[13];
    float mx = -1e30f;
    #pragma unroll
    for (int i = 0; i < 13; ++i) {
        int c = lane + (i << 6);
        if (c < n) { e[i] = a[c]; mx = fmaxf(mx, e[i]); }
        else e[i] = -1e30f;
    }
    mx = wave_max(mx);
    float ssum = 0.f;
    #pragma unroll
    for (int i = 0; i < 13; ++i) {
        int c = lane + (i << 6);
        if (c < n) { e[i] = expf(e[i] - mx); ssum += e[i]; }
    }
    ssum = wave_sum(ssum);
    #pragma unroll
    for (int i = 0; i < 13; ++i) {
        int c = lane + (i << 6);
        if (c < n) a[c] = e[i] / ssum;
    }
}

// ================= codebook norms: wave per row =================
__global__ __launch_bounds__(256)
void cnorm_kernel(const float* __restrict__ cb, float* __restrict__ cn)
{
    int wave = threadIdx.x >> 6, lane = threadIdx.x & 63;
    int row = (blockIdx.x << 2) + wave;
    if (row >= Kq) return;
    const float* cr = cb + (long)row * Dq;
    float4 v0 = *(const float4*)(cr + (lane << 2));
    float4 v1 = *(const float4*)(cr + 256 + (lane << 2));
    float ss = v0.x*v0.x + v0.y*v0.y + v0.z*v0.z + v0.w*v0.w
             + v1.x*v1.x + v1.y*v1.y + v1.z*v1.z + v1.w*v1.w;
    ss = wave_sum(ss);
    if (lane == 0) cn[row] = ss;
}

// ================= patchify / unpatchify / pos add =================
__global__ void patchify_kernel(const float* __restrict__ video, float* __restrict__ patches)
{
    long i = (long)blockIdx.x * 256 + threadIdx.x;
    if (i >= (long)TOKq * PINq) return;
    int row = (int)(i / PINq), col = (int)(i - (long)row * PINq);
    int c = col % 3; int q = col / 3;
    int pw = q & 15; q >>= 4;
    int ph = q & 15; int tpin = q >> 4;
    int wp = row % 14; int r2 = row / 14;
    int hp = r2 % 14; r2 /= 14;
    int tp = r2 & 3; int b = r2 >> 2;
    int tt = tp * 4 + tpin;
    int ih = hp * 16 + ph, iw = wp * 16 + pw;
    patches[i] = video[(((long)(b * 16 + tt) * 224 + ih) * 224 + iw) * 3 + c];
}

__global__ void unpatchify_kernel(const float* __restrict__ px, float* __restrict__ out)
{
    long o = (long)blockIdx.x * 256 + threadIdx.x;
    if (o >= RECN) return;
    int c = (int)(o % 3); long r = o / 3;
    int iw = (int)(r % 224); r /= 224;
    int ih = (int)(r % 224); r /= 224;
    int tt = (int)(r % 16); int b = (int)(r / 16);
    int tp = tt >> 2, tpin = tt & 3;
    int hp = ih >> 4, ph = ih & 15;
    int wp = iw >> 4, pw = iw & 15;
    long prow = ((long)(b * 4 + tp) * 14 + hp) * 14 + wp;
    int pcol = ((tpin * 16 + ph) * 16 + pw) * 3 + c;
    out[o] = px[prow * PINq + pcol];
}

__global__ void posadd_kernel(float* __restrict__ z, const float* __restrict__ pt,
                              const float* __restrict__ ph, const float* __restrict__ pw)
{
    long i = (long)blockIdx.x * 256 + threadIdx.x;
    if (i >= (long)TOKq * Dq) return;
    int d = (int)(i & 511); long r = i >> 9;
    int w = (int)(r % 14); r /= 14;
    int hh = (int)(r % 14); r /= 14;
    int tp = (int)(r & 3);
    z[i] += pt[tp * Dq + d] + ph[hh * Dq + d] + pw[w * Dq + d];
}

// ================= VQ argmin (block per token) =================
__global__ __launch_bounds__(256)
void argmin_kernel(const float* __restrict__ d2, int* __restrict__ idxb, float* __restrict__ out_idx)
{
    int tok = blockIdx.x;
    const float* r = d2 + (long)tok * Kq;
    float bv = 1e30f; int bi = 0x7fffffff;
    for (int k = threadIdx.x; k < Kq; k += 256) {
        float v = r[k];
        if (v < bv) { bv = v; bi = k; }
    }
    __shared__ float sv[256];
    __shared__ int   si[256];
    sv[threadIdx.x] = bv; si[threadIdx.x] = bi;
    __syncthreads();
    for (int s2 = 128; s2; s2 >>= 1) {
        if (threadIdx.x < s2) {
            float ov = sv[threadIdx.x + s2]; int oi = si[threadIdx.x + s2];
            if (ov < sv[threadIdx.x] || (ov == sv[threadIdx.x] && oi < si[threadIdx.x])) {
                sv[threadIdx.x] = ov; si[threadIdx.x] = oi;
            }
        }
        __syncthreads();
    }
    if (threadIdx.x == 0) { idxb[tok] = si[0]; out_idx[tok] = (float)si[0]; }
}

// ================= z_q gather + per-token SSE + counts =================
__global__ __launch_bounds__(256)
void zq_kernel(const float* __restrict__ cb, const int* __restrict__ idxb,
               const float* __restrict__ ze, float* __restrict__ zq,
               float* __restrict__ part, float* __restrict__ counts)
{
    int tok = blockIdx.x;
    int id = idxb[tok];
    const float* c = cb + (long)id * Dq;
    const float* z = ze + (long)tok * Dq;
    float* q = zq + (long)tok * Dq;
    float ss = 0.f;
    for (int d = threadIdx.x; d < Dq; d += 256) {
        float cv = c[d];
        q[d] = cv;
        float df = cv - z[d];
        ss += df * df;
    }
    float wsum = wave_sum(ss);
    __shared__ float sw[4];
    if ((threadIdx.x & 63) == 0) sw[threadIdx.x >> 6] = wsum;
    __syncthreads();
    if (threadIdx.x == 0) {
        part[tok] = sw[0] + sw[1] + sw[2] + sw[3];
        atomicAdd(&counts[id], 1.0f);   // integer-valued, order independent
    }
}

// ================= scalars: commit/cb_loss/perplexity =================
__global__ __launch_bounds__(256)
void scalars_kernel(const float* __restrict__ part, const float* __restrict__ counts,
                    float* __restrict__ out)
{
    float se = 0.f;
    for (int t = threadIdx.x; t < TOKq; t += 256) se += part[t];
    float pl = 0.f;
    for (int k = threadIdx.x; k < Kq; k += 256) {
        float p = counts[k] * (1.0f / 1568.0f);
        pl += p * logf(p + 1e-10f);
    }
    float wse = wave_sum(se), wpl = wave_sum(pl);
    __shared__ float s1[4], s2[4];
    if ((threadIdx.x & 63) == 0) { s1[threadIdx.x >> 6] = wse; s2[threadIdx.x >> 6] = wpl; }
    __syncthreads();
    if (threadIdx.x == 0) {
        float sse = s1[0] + s1[1] + s1[2] + s1[3];
        float plo = s2[0] + s2[1] + s2[2] + s2[3];
        float commit = sse / 802816.0f;   // mean over B*S*D
        out[RECN + 1568 + 0] = commit;
        out[RECN + 1568 + 1] = commit;
        out[RECN + 1568 + 2] = expf(-plo);
    }
}

// ================= host-side helpers =================
static void launch_gemm(hipStream_t st, int epi, bool trb,
                        const float* A, int lda, const float* B, int ldb,
                        const float* bias, const float* extra,
                        float* C, int ldc, int M, int N, int K, float alpha,
                        int nb, int bdiv,
                        long soA, long siA, long soB, long siB,
                        long soC, long siC, long soBias, long siBias)
{
    dim3 g((M + 63) / 64, (N + 63) / 64, nb), blk(256);
    int sel = epi * 2 + (trb ? 1 : 0);
    switch (sel) {
    case 0: gemm_f32<0,false><<<g,blk,0,st>>>(A,lda,B,ldb,bias,extra,C,ldc,M,N,K,alpha,bdiv,soA,siA,soB,siB,soC,siC,soBias,siBias); break;
    case 1: gemm_f32<0,true ><<<g,blk,0,st>>>(A,lda,B,ldb,bias,extra,C,ldc,M,N,K,alpha,bdiv,soA,siA,soB,siB,soC,siC,soBias,siBias); break;
    case 2: gemm_f32<1,false><<<g,blk,0,st>>>(A,lda,B,ldb,bias,extra,C,ldc,M,N,K,alpha,bdiv,soA,siA,soB,siB,soC,siC,soBias,siBias); break;
    case 4: gemm_f32<2,false><<<g,blk,0,st>>>(A,lda,B,ldb,bias,extra,C,ldc,M,N,K,alpha,bdiv,soA,siA,soB,siB,soC,siC,soBias,siBias); break;
    case 7: gemm_f32<3,true ><<<g,blk,0,st>>>(A,lda,B,ldb,bias,extra,C,ldc,M,N,K,alpha,bdiv,soA,siA,soB,siB,soC,siC,soBias,siBias); break;
    default: break;
    }
}

static void block_fwd(hipStream_t st, float* z, float* xln, float* qkv, float* att,
                      float* atto, float* hbuf,
                      const float* ln1s, const float* ln1b,
                      const float* Wqkv, const float* bqkv,
                      const float* Wo, const float* bo,
                      const float* ln2s, const float* ln2b,
                      const float* W1, const float* b1,
                      const float* W2, const float* b2)
{
    ln_kernel<<<TOKq / 4, 256, 0, st>>>(z, ln1s, ln1b, xln, TOKq);
    // qkv: 3 batched GEMMs into [TOK, 3D]
    launch_gemm(st, 0, false, xln, Dq, Wqkv, Dq, bqkv, nullptr, qkv, 3 * Dq,
                TOKq, Dq, Dq, 1.0f, 3, 3,
                0, 0, 0, (long)Dq * Dq, 0, Dq, 0, Dq);
    // scores = q @ k^T / 8 ; batch (b,h)
    launch_gemm(st, 0, true, qkv, 3 * Dq, qkv + Dq, 3 * Dq, nullptr, nullptr, att, Sq,
                Sq, Sq, HDq, 0.125f, Bq * NHq, NHq,
                (long)Sq * 3 * Dq, HDq, (long)Sq * 3 * Dq, HDq,
                (long)NHq * Sq * Sq, (long)Sq * Sq, 0, 0);
    softmax_kernel<<<(Bq * NHq * Sq) / 4, 256, 0, st>>>(att, Bq * NHq * Sq, Sq);
    // o = att @ v
    launch_gemm(st, 0, false, att, Sq, qkv + 2 * Dq, 3 * Dq, nullptr, nullptr, atto, Dq,
                Sq, HDq, Sq, 1.0f, Bq * NHq, NHq,
                (long)NHq * Sq * Sq, (long)Sq * Sq, (long)Sq * 3 * Dq, HDq,
                (long)Sq * Dq, HDq, 0, 0);
    // z += o @ Wo + bo
    launch_gemm(st, 1, false, atto, Dq, Wo, Dq, bo, nullptr, z, Dq,
                TOKq, Dq, Dq, 1.0f, 1, 1, 0,0,0,0,0,0,0,0);
    // FFN
    ln_kernel<<<TOKq / 4, 256, 0, st>>>(z, ln2s, ln2b, xln, TOKq);
    launch_gemm(st, 2, false, xln, Dq, W1, DFFq, b1, nullptr, hbuf, DFFq,
                TOKq, DFFq, Dq, 1.0f, 1, 1, 0,0,0,0,0,0,0,0);
    launch_gemm(st, 1, false, hbuf, DFFq, W2, Dq, b2, nullptr, z, Dq,
                TOKq, Dq, DFFq, 1.0f, 1, 1, 0,0,0,0,0,0,0,0);
}

extern "C" void kernel_launch(void* const* d_in, const int* in_sizes, int n_in,
                              void* d_out, int out_size, void* d_ws, size_t ws_size,
                              hipStream_t stream)
{
    (void)in_sizes; (void)n_in; (void)out_size;
    if (ws_size < (size_t)OFF_END * sizeof(float)) return;

    const float* video = (const float*)d_in[0];
    const float* epW   = (const float*)d_in[1];  const float* epb   = (const float*)d_in[2];
    const float* ept   = (const float*)d_in[3];  const float* ephp  = (const float*)d_in[4];
    const float* epwp  = (const float*)d_in[5];
    const float* eln1s = (const float*)d_in[6];  const float* eln1b = (const float*)d_in[7];
    const float* eWqkv = (const float*)d_in[8];  const float* ebqkv = (const float*)d_in[9];
    const float* eWo   = (const float*)d_in[10]; const float* ebo   = (const float*)d_in[11];
    const float* eln2s = (const float*)d_in[12]; const float* eln2b = (const float*)d_in[13];
    const float* eW1   = (const float*)d_in[14]; const float* eb1   = (const float*)d_in[15];
    const float* eW2   = (const float*)d_in[16]; const float* eb2   = (const float*)d_in[17];
    const float* elnfs = (const float*)d_in[18]; const float* elnfb = (const float*)d_in[19];
    const float* ecbW  = (const float*)d_in[20]; const float* ecbb  = (const float*)d_in[21];
    const float* cbook = (const float*)d_in[22];
    const float* dcbW  = (const float*)d_in[23]; const float* dcbb  = (const float*)d_in[24];
    const float* dpt   = (const float*)d_in[25]; const float* dphp  = (const float*)d_in[26];
    const float* dpwp  = (const float*)d_in[27];
    const float* dln1s = (const float*)d_in[28]; const float* dln1b = (const float*)d_in[29];
    const float* dWqkv = (const float*)d_in[30]; const float* dbqkv = (const float*)d_in[31];
    const float* dWo   = (const float*)d_in[32]; const float* dbo   = (const float*)d_in[33];
    const float* dln2s = (const float*)d_in[34]; const float* dln2b = (const float*)d_in[35];
    const float* dW1   = (const float*)d_in[36]; const float* db1   = (const float*)d_in[37];
    const float* dW2   = (const float*)d_in[38]; const float* db2   = (const float*)d_in[39];
    const float* dlnfs = (const float*)d_in[40]; const float* dlnfb = (const float*)d_in[41];
    const float* dpxW  = (const float*)d_in[42]; const float* dpxb  = (const float*)d_in[43];

    float* ws   = (float*)d_ws;
    float* big  = ws + OFF_BIG;     // patches / att / d2 / px (time-shared)
    float* z    = ws + OFF_Z;
    float* xln  = ws + OFF_XLN;
    float* qkv  = ws + OFF_QKV;
    float* atto = ws + OFF_ATTO;
    float* hbuf = ws + OFF_H;
    float* ze   = ws + OFF_ZE;
    float* zq   = ws + OFF_ZQ;
    float* cn   = ws + OFF_CN;
    int*   idxb = (int*)(ws + OFF_IDX);
    float* cnt  = ws + OFF_CNT;
    float* part = ws + OFF_PART;
    float* out  = (float*)d_out;

    // zero the count bins (graph-capture-safe)
    hipMemsetAsync(cnt, 0, Kq * sizeof(float), stream);

    // codebook norms
    cnorm_kernel<<<Kq / 4, 256, 0, stream>>>(cbook, cn);

    // ---- encoder front ----
    patchify_kernel<<<(int)(((long)TOKq * PINq + 255) / 256), 256, 0, stream>>>(video, big);
    launch_gemm(stream, 0, false, big, PINq, epW, Dq, epb, nullptr, z, Dq,
                TOKq, Dq, PINq, 1.0f, 1, 1, 0,0,0,0,0,0,0,0);
    posadd_kernel<<<(int)(((long)TOKq * Dq + 255) / 256), 256, 0, stream>>>(z, ept, ephp, epwp);

    for (int l = 0; l < Lq; ++l)
        block_fwd(stream, z, xln, qkv, big, atto, hbuf,
                  eln1s + l * Dq, eln1b + l * Dq,
                  eWqkv + (long)l * 3 * Dq * Dq, ebqkv + l * 3 * Dq,
                  eWo + (long)l * Dq * Dq, ebo + l * Dq,
                  eln2s + l * Dq, eln2b + l * Dq,
                  eW1 + (long)l * Dq * DFFq, eb1 + l * DFFq,
                  eW2 + (long)l * DFFq * Dq, eb2 + l * Dq);

    ln_kernel<<<TOKq / 4, 256, 0, stream>>>(z, elnfs, elnfb, xln, TOKq);
    launch_gemm(stream, 0, false, xln, Dq, ecbW, Dq, ecbb, nullptr, ze, Dq,
                TOKq, Dq, Dq, 1.0f, 1, 1, 0,0,0,0,0,0,0,0);

    // ---- VQ ----
    // d2' = |c|^2 - 2 z.c  (row-constant |z|^2 irrelevant for argmin)
    launch_gemm(stream, 3, true, ze, Dq, cbook, Dq, nullptr, cn, big, Kq,
                TOKq, Kq, Dq, 1.0f, 1, 1, 0,0,0,0,0,0,0,0);
    argmin_kernel<<<TOKq, 256, 0, stream>>>(big, idxb, out + RECN);
    zq_kernel<<<TOKq, 256, 0, stream>>>(cbook, idxb, ze, zq, part, cnt);
    scalars_kernel<<<1, 256, 0, stream>>>(part, cnt, out);

    // ---- decoder ----
    launch_gemm(stream, 0, false, zq, Dq, dcbW, Dq, dcbb, nullptr, z, Dq,
                TOKq, Dq, Dq, 1.0f, 1, 1, 0,0,0,0,0,0,0,0);
    posadd_kernel<<<(int)(((long)TOKq * Dq + 255) / 256), 256, 0, stream>>>(z, dpt, dphp, dpwp);

    for (int l = 0; l < Lq; ++l)
        block_fwd(stream, z, xln, qkv, big, atto, hbuf,
                  dln1s + l * Dq, dln1b + l * Dq,
                  dWqkv + (long)l * 3 * Dq * Dq, dbqkv + l * 3 * Dq,
                  dWo + (long)l * Dq * Dq, dbo + l * Dq,
                  dln2s + l * Dq, dln2b + l * Dq,
                  dW1 + (long)l * Dq * DFFq, db1 + l * DFFq,
                  dW2 + (long)l * DFFq * Dq, db2 + l * Dq);

    ln_kernel<<<TOKq / 4, 256, 0, stream>>>(z, dlnfs, dlnfb, xln, TOKq);
    launch_gemm(stream, 0, false, xln, Dq, dpxW, PINq, dpxb, nullptr, big, PINq,
                TOKq, PINq, Dq, 1.0f, 1, 1, 0,0,0,0,0,0,0,0);
    unpatchify_kernel<<<(int)((RECN + 255) / 256), 256, 0, stream>>>(big, out);
}

// Round 2
// 3094.951 us; speedup vs baseline: 1.8920x; 1.8920x over previous
//
#include <hip/hip_runtime.h>
#include <math.h>

// ---- problem dims ----
#define Bq    2
#define Dq    512
#define DFFq  2048
#define Lq    6
#define NHq   8
#define HDq   64
#define Kq    8192
#define Sq    784
#define PINq  3072
#define TOKq  1568            // B*S
#define RECN  4816896L        // B*T*IH*IW*C

// ---- workspace layout (float offsets) ----
#define OFF_BIG  0L
#define SZ_BIG   12845056L
#define OFF_Z    (OFF_BIG + SZ_BIG)
#define OFF_XLN  (OFF_Z    + 802816L)
#define OFF_QKV  (OFF_XLN  + 802816L)
#define OFF_ATTO (OFF_QKV  + 2408448L)
#define OFF_H    (OFF_ATTO + 802816L)
#define OFF_ZE   (OFF_H    + 3211264L)
#define OFF_ZQ   (OFF_ZE   + 802816L)
#define OFF_CN   (OFF_ZQ   + 802816L)
#define OFF_IDX  (OFF_CN   + 8192L)
#define OFF_CNT  (OFF_IDX  + 1568L)
#define OFF_PART (OFF_CNT  + 8192L)
#define OFF_END  (OFF_PART + 1568L)

#define CEXT 802816L          // full C extent of the split GEMMs (1568*512)

typedef short bf16x8 __attribute__((ext_vector_type(8)));
typedef float f32x4  __attribute__((ext_vector_type(4)));
typedef unsigned short u16;

#define LP 40                 // LDS row pitch (ushorts): 80B rows, 16B-aligned

// ================= wave reductions =================
__device__ __forceinline__ float wave_sum(float v) {
    #pragma unroll
    for (int o = 32; o; o >>= 1) v += __shfl_xor(v, o);
    return v;
}
__device__ __forceinline__ float wave_max(float v) {
    #pragma unroll
    for (int o = 32; o; o >>= 1) v = fmaxf(v, __shfl_xor(v, o));
    return v;
}
__device__ __forceinline__ float gelu_f(float x) {
    float x3 = x * x * x;
    return 0.5f * x * (1.0f + tanhf(0.7978845608028654f * (x + 0.044715f * x3)));
}

// split f32 -> bf16 hi (RNE) + bf16 lo (truncated residual)
__device__ __forceinline__ void split_f32(float x, u16& h, u16& l) {
    unsigned u = __float_as_uint(x);
    unsigned t = u + 0x7fffu + ((u >> 16) & 1u);
    h = (u16)(t >> 16);
    float r = x - __uint_as_float((t >> 16) << 16);
    l = (u16)(__float_as_uint(r) >> 16);
}

// ================= MFMA bf16x3 GEMM =================
// C = epi( A[M,K] @ B )   TRB: B stored [N,K] row-major else [K,N]
// MATH 0: alpha*acc + bias[n]; 2: gelu(acc+bias[n]); 3: extra[n] - 2*acc
// ksplit>1: raw partials to part (mirrors C layout) at zk*pstride
template<int MATH, bool TRB>
__global__ __launch_bounds__(256)
void gemm_mx(const float* __restrict__ A, int lda,
             const float* __restrict__ B, int ldb,
             const float* __restrict__ bias,
             const float* __restrict__ extra,
             float* __restrict__ C, int ldc,
             float* __restrict__ part, long pstride,
             int M, int N, int K, float alpha, int bdiv, int ksplit, int klen,
             long soA, long siA, long soB, long siB,
             long soC, long siC, long soBias, long siBias)
{
    __shared__ u16 Ah[64 * LP], Al[64 * LP], Bh[64 * LP], Bl[64 * LP];

    const int zb2 = blockIdx.z;
    const int zk = zb2 % ksplit, zb = zb2 / ksplit;
    const int zo = zb / bdiv,    zi = zb - zo * bdiv;
    A += zo * soA + zi * siA;
    B += zo * soB + zi * siB;
    if (bias) bias += zo * soBias + zi * siBias;

    const int t = threadIdx.x;
    const int m0 = blockIdx.x << 6, n0 = blockIdx.y << 6;
    const int kbeg = zk * klen;
    const int kend = (kbeg + klen < K) ? kbeg + klen : K;

    const int w = t >> 6, lane = t & 63;
    const int wm = w >> 1, wn = w & 1;
    const int l15 = lane & 15, lk = (lane >> 4) << 3;

    // staging maps
    const int ar = t >> 2, ac = (t & 3) << 2;     // A / TRB-B: 64 rows x (4+4) k
    const int kr = t >> 3, nc = (t & 7) << 2;     // non-TRB B: 32 k x (4+4) n

    f32x4 acc[2][2] = {};

    for (int k0 = kbeg; k0 < kend; k0 += 32) {
        // ---- stage A (and TRB B) : [64 rows][32 k] ----
        {
            int grA = m0 + ar; grA = grA < M - 1 ? grA : M - 1;
            const float* Ap = A + (long)grA * lda;
            #pragma unroll
            for (int p = 0; p < 2; ++p) {
                int k = k0 + ac + (p << 4);
                float4 v = make_float4(0.f, 0.f, 0.f, 0.f);
                if (k < kend) v = *(const float4*)(Ap + k);
                u16 h0,h1,h2,h3,l0,l1,l2,l3;
                split_f32(v.x, h0, l0); split_f32(v.y, h1, l1);
                split_f32(v.z, h2, l2); split_f32(v.w, h3, l3);
                uint2 ph, pl;
                ph.x = (unsigned)h0 | ((unsigned)h1 << 16); ph.y = (unsigned)h2 | ((unsigned)h3 << 16);
                pl.x = (unsigned)l0 | ((unsigned)l1 << 16); pl.y = (unsigned)l2 | ((unsigned)l3 << 16);
                int off = ar * LP + ac + (p << 4);
                *(uint2*)&Ah[off] = ph;
                *(uint2*)&Al[off] = pl;
            }
        }
        if (TRB) {
            int grB = n0 + ar; grB = grB < N - 1 ? grB : N - 1;
            const float* Bp = B + (long)grB * ldb;
            #pragma unroll
            for (int p = 0; p < 2; ++p) {
                int k = k0 + ac + (p << 4);
                float4 v = make_float4(0.f, 0.f, 0.f, 0.f);
                if (k < kend) v = *(const float4*)(Bp + k);
                u16 h0,h1,h2,h3,l0,l1,l2,l3;
                split_f32(v.x, h0, l0); split_f32(v.y, h1, l1);
                split_f32(v.z, h2, l2); split_f32(v.w, h3, l3);
                uint2 ph, pl;
                ph.x = (unsigned)h0 | ((unsigned)h1 << 16); ph.y = (unsigned)h2 | ((unsigned)h3 << 16);
                pl.x = (unsigned)l0 | ((unsigned)l1 << 16); pl.y = (unsigned)l2 | ((unsigned)l3 << 16);
                int off = ar * LP + ac + (p << 4);
                *(uint2*)&Bh[off] = ph;
                *(uint2*)&Bl[off] = pl;
            }
        } else {
            // B is [K][N]: transpose into LDS [n][k]
            #pragma unroll
            for (int p = 0; p < 2; ++p) {
                int k = k0 + kr;
                int n = nc + (p << 5);
                float4 v = make_float4(0.f, 0.f, 0.f, 0.f);
                if (k < kend) v = *(const float4*)(B + (long)k * ldb + n0 + n);
                u16 h, l;
                split_f32(v.x, h, l); Bh[(n+0)*LP + kr] = h; Bl[(n+0)*LP + kr] = l;
                split_f32(v.y, h, l); Bh[(n+1)*LP + kr] = h; Bl[(n+1)*LP + kr] = l;
                split_f32(v.z, h, l); Bh[(n+2)*LP + kr] = h; Bl[(n+2)*LP + kr] = l;
                split_f32(v.w, h, l); Bh[(n+3)*LP + kr] = h; Bl[(n+3)*LP + kr] = l;
            }
        }
        __syncthreads();

        // ---- fragments + MFMA ----
        bf16x8 ah[2], al2[2], bh[2], bl2[2];
        #pragma unroll
        for (int mi = 0; mi < 2; ++mi) {
            int row = (wm << 5) + (mi << 4) + l15;
            ah[mi]  = *(const bf16x8*)&Ah[row * LP + lk];
            al2[mi] = *(const bf16x8*)&Al[row * LP + lk];
        }
        #pragma unroll
        for (int ni = 0; ni < 2; ++ni) {
            int row = (wn << 5) + (ni << 4) + l15;
            bh[ni]  = *(const bf16x8*)&Bh[row * LP + lk];
            bl2[ni] = *(const bf16x8*)&Bl[row * LP + lk];
        }
        #pragma unroll
        for (int mi = 0; mi < 2; ++mi)
            #pragma unroll
            for (int ni = 0; ni < 2; ++ni) {
                acc[mi][ni] = __builtin_amdgcn_mfma_f32_16x16x32_bf16(ah[mi],  bh[ni],  acc[mi][ni], 0, 0, 0);
                acc[mi][ni] = __builtin_amdgcn_mfma_f32_16x16x32_bf16(ah[mi],  bl2[ni], acc[mi][ni], 0, 0, 0);
                acc[mi][ni] = __builtin_amdgcn_mfma_f32_16x16x32_bf16(al2[mi], bh[ni],  acc[mi][ni], 0, 0, 0);
            }
        __syncthreads();
    }

    // ---- write ----
    if (ksplit > 1) {
        float* P = part + (long)zk * pstride + zo * soC + zi * siC;
        #pragma unroll
        for (int mi = 0; mi < 2; ++mi)
            #pragma unroll
            for (int ni = 0; ni < 2; ++ni) {
                int gn = n0 + (wn << 5) + (ni << 4) + l15;
                if (gn >= N) continue;
                int gmb = m0 + (wm << 5) + (mi << 4) + ((lane >> 4) << 2);
                #pragma unroll
                for (int r = 0; r < 4; ++r) {
                    int gm = gmb + r;
                    if (gm < M) P[(long)gm * ldc + gn] = acc[mi][ni][r];
                }
            }
        return;
    }
    C += zo * soC + zi * siC;
    #pragma unroll
    for (int mi = 0; mi < 2; ++mi)
        #pragma unroll
        for (int ni = 0; ni < 2; ++ni) {
            int gn = n0 + (wn << 5) + (ni << 4) + l15;
            if (gn >= N) continue;
            int gmb = m0 + (wm << 5) + (mi << 4) + ((lane >> 4) << 2);
            #pragma unroll
            for (int r = 0; r < 4; ++r) {
                int gm = gmb + r;
                if (gm >= M) continue;
                float v = acc[mi][ni][r];
                if (MATH == 0)      v = alpha * v + (bias ? bias[gn] : 0.0f);
                else if (MATH == 2) v = gelu_f(v + bias[gn]);
                else                v = extra[gn] - 2.0f * v;
                C[(long)gm * ldc + gn] = v;
            }
        }
}

// ================= split-K reduce + epilogue =================
// MATH 0: C[i] = sum + bias[col]; MATH 1: C[i] += sum + bias[col]
template<int MATH>
__global__ __launch_bounds__(256)
void reduce_k(const float* __restrict__ part, long pstride, int ks,
              const float* __restrict__ bias, int ldc,
              float* __restrict__ C, long total)
{
    long i = (long)blockIdx.x * 256 + threadIdx.x;
    if (i >= total) return;
    float s = 0.f;
    for (int k = 0; k < ks; ++k) s += part[(long)k * pstride + i];
    int col = (int)(i % ldc);
    float b = bias ? bias[col] : 0.0f;
    if (MATH == 0) C[i] = s + b;
    else           C[i] += s + b;
}

// ================= LayerNorm: wave per row (D=512) =================
__global__ __launch_bounds__(256)
void ln_kernel(const float* __restrict__ x, const float* __restrict__ s,
               const float* __restrict__ b, float* __restrict__ y, int rows)
{
    int wave = threadIdx.x >> 6, lane = threadIdx.x & 63;
    int row = (blockIdx.x << 2) + wave;
    if (row >= rows) return;
    const float* xr = x + (long)row * Dq;
    float4 v0 = *(const float4*)(xr + (lane << 2));
    float4 v1 = *(const float4*)(xr + 256 + (lane << 2));
    float sum = v0.x + v0.y + v0.z + v0.w + v1.x + v1.y + v1.z + v1.w;
    sum = wave_sum(sum);
    float m = sum * (1.0f / 512.0f);
    float d0x = v0.x - m, d0y = v0.y - m, d0z = v0.z - m, d0w = v0.w - m;
    float d1x = v1.x - m, d1y = v1.y - m, d1z = v1.z - m, d1w = v1.w - m;
    float vs = d0x*d0x + d0y*d0y + d0z*d0z + d0w*d0w + d1x*d1x + d1y*d1y + d1z*d1z + d1w*d1w;
    vs = wave_sum(vs);
    float rstd = 1.0f / sqrtf(vs * (1.0f / 512.0f) + 1e-6f);
    float* yr = y + (long)row * Dq;
    int c0 = lane << 2;
    float4 o0, o1;
    o0.x = d0x * rstd * s[c0+0] + b[c0+0];
    o0.y = d0y * rstd * s[c0+1] + b[c0+1];
    o0.z = d0z * rstd * s[c0+2] + b[c0+2];
    o0.w = d0w * rstd * s[c0+3] + b[c0+3];
    o1.x = d1x * rstd * s[256+c0+0] + b[256+c0+0];
    o1.y = d1y * rstd * s[256+c0+1] + b[256+c0+1];
    o1.z = d1z * rstd * s[256+c0+2] + b[256+c0+2];
    o1.w = d1w * rstd * s[256+c0+3] + b[256+c0+3];
    *(float4*)(yr + c0) = o0;
    *(float4*)(yr + 256 + c0) = o1;
}

// ================= softmax: wave per row (n=784) =================
__global__ __launch_bounds__(256)
void softmax_kernel(float* __restrict__ att, int rows, int n)
{
    int wave = threadIdx.x >> 6, lane = threadIdx.x & 63;
    int row = (blockIdx.x << 2) + wave;
    if (row >= rows) return;
    float* a = att + (long)row * n;
    float e[13];
    float mx = -1e30f;
    #pragma unroll
    for (int i = 0; i < 13; ++i) {
        int c = lane + (i << 6);
        if (c < n) { e[i] = a[c]; mx = fmaxf(mx, e[i]); }
        else e[i] = -1e30f;
    }
    mx = wave_max(mx);
    float ssum = 0.f;
    #pragma unroll
    for (int i = 0; i < 13; ++i) {
        int c = lane + (i << 6);
        if (c < n) { e[i] = expf(e[i] - mx); ssum += e[i]; }
    }
    ssum = wave_sum(ssum);
    #pragma unroll
    for (int i = 0; i < 13; ++i) {
        int c = lane + (i << 6);
        if (c < n) a[c] = e[i] / ssum;
    }
}

// ================= codebook norms =================
__global__ __launch_bounds__(256)
void cnorm_kernel(const float* __restrict__ cb, float* __restrict__ cn)
{
    int wave = threadIdx.x >> 6, lane = threadIdx.x & 63;
    int row = (blockIdx.x << 2) + wave;
    if (row >= Kq) return;
    const float* cr = cb + (long)row * Dq;
    float4 v0 = *(const float4*)(cr + (lane << 2));
    float4 v1 = *(const float4*)(cr + 256 + (lane << 2));
    float ss = v0.x*v0.x + v0.y*v0.y + v0.z*v0.z + v0.w*v0.w
             + v1.x*v1.x + v1.y*v1.y + v1.z*v1.z + v1.w*v1.w;
    ss = wave_sum(ss);
    if (lane == 0) cn[row] = ss;
}

// ================= patchify / unpatchify / pos add =================
__global__ void patchify_kernel(const float* __restrict__ video, float* __restrict__ patches)
{
    long i = (long)blockIdx.x * 256 + threadIdx.x;
    if (i >= (long)TOKq * PINq) return;
    int row = (int)(i / PINq), col = (int)(i - (long)row * PINq);
    int c = col % 3; int q = col / 3;
    int pw = q & 15; q >>= 4;
    int ph = q & 15; int tpin = q >> 4;
    int wp = row % 14; int r2 = row / 14;
    int hp = r2 % 14; r2 /= 14;
    int tp = r2 & 3; int b = r2 >> 2;
    int tt = tp * 4 + tpin;
    int ih = hp * 16 + ph, iw = wp * 16 + pw;
    patches[i] = video[(((long)(b * 16 + tt) * 224 + ih) * 224 + iw) * 3 + c];
}

__global__ void unpatchify_kernel(const float* __restrict__ px, float* __restrict__ out)
{
    long o = (long)blockIdx.x * 256 + threadIdx.x;
    if (o >= RECN) return;
    int c = (int)(o % 3); long r = o / 3;
    int iw = (int)(r % 224); r /= 224;
    int ih = (int)(r % 224); r /= 224;
    int tt = (int)(r % 16); int b = (int)(r / 16);
    int tp = tt >> 2, tpin = tt & 3;
    int hp = ih >> 4, ph = ih & 15;
    int wp = iw >> 4, pw = iw & 15;
    long prow = ((long)(b * 4 + tp) * 14 + hp) * 14 + wp;
    int pcol = ((tpin * 16 + ph) * 16 + pw) * 3 + c;
    out[o] = px[prow * PINq + pcol];
}

__global__ void posadd_kernel(float* __restrict__ z, const float* __restrict__ pt,
                              const float* __restrict__ ph, const float* __restrict__ pw)
{
    long i = (long)blockIdx.x * 256 + threadIdx.x;
    if (i >= (long)TOKq * Dq) return;
    int d = (int)(i & 511); long r = i >> 9;
    int w = (int)(r % 14); r /= 14;
    int hh = (int)(r % 14); r /= 14;
    int tp = (int)(r & 3);
    z[i] += pt[tp * Dq + d] + ph[hh * Dq + d] + pw[w * Dq + d];
}

// ================= VQ argmin =================
__global__ __launch_bounds__(256)
void argmin_kernel(const float* __restrict__ d2, int* __restrict__ idxb, float* __restrict__ out_idx)
{
    int tok = blockIdx.x;
    const float* r = d2 + (long)tok * Kq;
    float bv = 1e30f; int bi = 0x7fffffff;
    for (int k = threadIdx.x; k < Kq; k += 256) {
        float v = r[k];
        if (v < bv) { bv = v; bi = k; }
    }
    __shared__ float sv[256];
    __shared__ int   si[256];
    sv[threadIdx.x] = bv; si[threadIdx.x] = bi;
    __syncthreads();
    for (int s2 = 128; s2; s2 >>= 1) {
        if (threadIdx.x < s2) {
            float ov = sv[threadIdx.x + s2]; int oi = si[threadIdx.x + s2];
            if (ov < sv[threadIdx.x] || (ov == sv[threadIdx.x] && oi < si[threadIdx.x])) {
                sv[threadIdx.x] = ov; si[threadIdx.x] = oi;
            }
        }
        __syncthreads();
    }
    if (threadIdx.x == 0) { idxb[tok] = si[0]; out_idx[tok] = (float)si[0]; }
}

// ================= z_q gather + per-token SSE + counts =================
__global__ __launch_bounds__(256)
void zq_kernel(const float* __restrict__ cb, const int* __restrict__ idxb,
               const float* __restrict__ ze, float* __restrict__ zq,
               float* __restrict__ part, float* __restrict__ counts)
{
    int tok = blockIdx.x;
    int id = idxb[tok];
    const float* c = cb + (long)id * Dq;
    const float* z = ze + (long)tok * Dq;
    float* q = zq + (long)tok * Dq;
    float ss = 0.f;
    for (int d = threadIdx.x; d < Dq; d += 256) {
        float cv = c[d];
        q[d] = cv;
        float df = cv - z[d];
        ss += df * df;
    }
    float wsum = wave_sum(ss);
    __shared__ float sw[4];
    if ((threadIdx.x & 63) == 0) sw[threadIdx.x >> 6] = wsum;
    __syncthreads();
    if (threadIdx.x == 0) {
        part[tok] = sw[0] + sw[1] + sw[2] + sw[3];
        atomicAdd(&counts[id], 1.0f);
    }
}

// ================= scalars =================
__global__ __launch_bounds__(256)
void scalars_kernel(const float* __restrict__ part, const float* __restrict__ counts,
                    float* __restrict__ out)
{
    float se = 0.f;
    for (int t = threadIdx.x; t < TOKq; t += 256) se += part[t];
    float pl = 0.f;
    for (int k = threadIdx.x; k < Kq; k += 256) {
        float p = counts[k] * (1.0f / 1568.0f);
        pl += p * logf(p + 1e-10f);
    }
    float wse = wave_sum(se), wpl = wave_sum(pl);
    __shared__ float s1[4], s2[4];
    if ((threadIdx.x & 63) == 0) { s1[threadIdx.x >> 6] = wse; s2[threadIdx.x >> 6] = wpl; }
    __syncthreads();
    if (threadIdx.x == 0) {
        float sse = s1[0] + s1[1] + s1[2] + s1[3];
        float plo = s2[0] + s2[1] + s2[2] + s2[3];
        float commit = sse / 802816.0f;
        out[RECN + 1568 + 0] = commit;
        out[RECN + 1568 + 1] = commit;
        out[RECN + 1568 + 2] = expf(-plo);
    }
}

// ================= host-side helpers =================
static void launch_gemm(hipStream_t st, int math, bool trb,
                        const float* A, int lda, const float* B, int ldb,
                        const float* bias, const float* extra,
                        float* C, int ldc, float* part, long pstride,
                        int M, int N, int K, float alpha,
                        int nb, int bdiv, int ksplit, int klen,
                        long soA, long siA, long soB, long siB,
                        long soC, long siC, long soBias, long siBias)
{
    dim3 g((M + 63) / 64, (N + 63) / 64, nb * ksplit), blk(256);
    if (math == 0 && !trb)
        gemm_mx<0,false><<<g,blk,0,st>>>(A,lda,B,ldb,bias,extra,C,ldc,part,pstride,M,N,K,alpha,bdiv,ksplit,klen,soA,siA,soB,siB,soC,siC,soBias,siBias);
    else if (math == 0 && trb)
        gemm_mx<0,true ><<<g,blk,0,st>>>(A,lda,B,ldb,bias,extra,C,ldc,part,pstride,M,N,K,alpha,bdiv,ksplit,klen,soA,siA,soB,siB,soC,siC,soBias,siBias);
    else if (math == 2)
        gemm_mx<2,false><<<g,blk,0,st>>>(A,lda,B,ldb,bias,extra,C,ldc,part,pstride,M,N,K,alpha,bdiv,ksplit,klen,soA,siA,soB,siB,soC,siC,soBias,siBias);
    else
        gemm_mx<3,true ><<<g,blk,0,st>>>(A,lda,B,ldb,bias,extra,C,ldc,part,pstride,M,N,K,alpha,bdiv,ksplit,klen,soA,siA,soB,siB,soC,siC,soBias,siBias);
}

static void launch_reduce(hipStream_t st, int math, const float* part, long pstride, int ks,
                          const float* bias, int ldc, float* C, long total)
{
    int g = (int)((total + 255) / 256);
    if (math == 0) reduce_k<0><<<g,256,0,st>>>(part, pstride, ks, bias, ldc, C, total);
    else           reduce_k<1><<<g,256,0,st>>>(part, pstride, ks, bias, ldc, C, total);
}

static void block_fwd(hipStream_t st, float* z, float* xln, float* qkv, float* att,
                      float* atto, float* hbuf, float* big,
                      const float* ln1s, const float* ln1b,
                      const float* Wqkv, const float* bqkv,
                      const float* Wo, const float* bo,
                      const float* ln2s, const float* ln2b,
                      const float* W1, const float* b1,
                      const float* W2, const float* b2)
{
    ln_kernel<<<TOKq / 4, 256, 0, st>>>(z, ln1s, ln1b, xln, TOKq);
    // qkv (batched x3, unsplit, bias epilogue)
    launch_gemm(st, 0, false, xln, Dq, Wqkv, Dq, bqkv, nullptr, qkv, 3 * Dq, nullptr, 0,
                TOKq, Dq, Dq, 1.0f, 3, 3, 1, Dq,
                0, 0, 0, (long)Dq * Dq, 0, Dq, 0, Dq);
    // scores = q @ k^T / 8 (batched b*h, TRB, unsplit)
    launch_gemm(st, 0, true, qkv, 3 * Dq, qkv + Dq, 3 * Dq, nullptr, nullptr, att, Sq, nullptr, 0,
                Sq, Sq, HDq, 0.125f, Bq * NHq, NHq, 1, HDq,
                (long)Sq * 3 * Dq, HDq, (long)Sq * 3 * Dq, HDq,
                (long)NHq * Sq * Sq, (long)Sq * Sq, 0, 0);
    softmax_kernel<<<(Bq * NHq * Sq) / 4, 256, 0, st>>>(att, Bq * NHq * Sq, Sq);
    // o = att @ v  (batched, split-K 4 -> partials in hbuf)
    launch_gemm(st, 0, false, att, Sq, qkv + 2 * Dq, 3 * Dq, nullptr, nullptr, atto, Dq, hbuf, CEXT,
                Sq, HDq, Sq, 1.0f, Bq * NHq, NHq, 4, 224,
                (long)NHq * Sq * Sq, (long)Sq * Sq, (long)Sq * 3 * Dq, HDq,
                (long)Sq * Dq, HDq, 0, 0);
    launch_reduce(st, 0, hbuf, CEXT, 4, nullptr, Dq, atto, CEXT);
    // z += o @ Wo + bo  (split-K 4 -> hbuf, resid reduce)
    launch_gemm(st, 0, false, atto, Dq, Wo, Dq, nullptr, nullptr, nullptr, Dq, hbuf, CEXT,
                TOKq, Dq, Dq, 1.0f, 1, 1, 4, 128, 0,0,0,0,0,0,0,0);
    launch_reduce(st, 1, hbuf, CEXT, 4, bo, Dq, z, CEXT);
    // FFN
    ln_kernel<<<TOKq / 4, 256, 0, st>>>(z, ln2s, ln2b, xln, TOKq);
    launch_gemm(st, 2, false, xln, Dq, W1, DFFq, b1, nullptr, hbuf, DFFq, nullptr, 0,
                TOKq, DFFq, Dq, 1.0f, 1, 1, 1, Dq, 0,0,0,0,0,0,0,0);
    launch_gemm(st, 0, false, hbuf, DFFq, W2, Dq, nullptr, nullptr, nullptr, Dq, big, CEXT,
                TOKq, Dq, DFFq, 1.0f, 1, 1, 4, 512, 0,0,0,0,0,0,0,0);
    launch_reduce(st, 1, big, CEXT, 4, b2, Dq, z, CEXT);
}

extern "C" void kernel_launch(void* const* d_in, const int* in_sizes, int n_in,
                              void* d_out, int out_size, void* d_ws, size_t ws_size,
                              hipStream_t stream)
{
    (void)in_sizes; (void)n_in; (void)out_size;
    if (ws_size < (size_t)OFF_END * sizeof(float)) return;

    const float* video = (const float*)d_in[0];
    const float* epW   = (const float*)d_in[1];  const float* epb   = (const float*)d_in[2];
    const float* ept   = (const float*)d_in[3];  const float* ephp  = (const float*)d_in[4];
    const float* epwp  = (const float*)d_in[5];
    const float* eln1s = (const float*)d_in[6];  const float* eln1b = (const float*)d_in[7];
    const float* eWqkv = (const float*)d_in[8];  const float* ebqkv = (const float*)d_in[9];
    const float* eWo   = (const float*)d_in[10]; const float* ebo   = (const float*)d_in[11];
    const float* eln2s = (const float*)d_in[12]; const float* eln2b = (const float*)d_in[13];
    const float* eW1   = (const float*)d_in[14]; const float* eb1   = (const float*)d_in[15];
    const float* eW2   = (const float*)d_in[16]; const float* eb2   = (const float*)d_in[17];
    const float* elnfs = (const float*)d_in[18]; const float* elnfb = (const float*)d_in[19];
    const float* ecbW  = (const float*)d_in[20]; const float* ecbb  = (const float*)d_in[21];
    const float* cbook = (const float*)d_in[22];
    const float* dcbW  = (const float*)d_in[23]; const float* dcbb  = (const float*)d_in[24];
    const float* dpt   = (const float*)d_in[25]; const float* dphp  = (const float*)d_in[26];
    const float* dpwp  = (const float*)d_in[27];
    const float* dln1s = (const float*)d_in[28]; const float* dln1b = (const float*)d_in[29];
    const float* dWqkv = (const float*)d_in[30]; const float* dbqkv = (const float*)d_in[31];
    const float* dWo   = (const float*)d_in[32]; const float* dbo   = (const float*)d_in[33];
    const float* dln2s = (const float*)d_in[34]; const float* dln2b = (const float*)d_in[35];
    const float* dW1   = (const float*)d_in[36]; const float* db1   = (const float*)d_in[37];
    const float* dW2   = (const float*)d_in[38]; const float* db2   = (const float*)d_in[39];
    const float* dlnfs = (const float*)d_in[40]; const float* dlnfb = (const float*)d_in[41];
    const float* dpxW  = (const float*)d_in[42]; const float* dpxb  = (const float*)d_in[43];

    float* ws   = (float*)d_ws;
    float* big  = ws + OFF_BIG;
    float* z    = ws + OFF_Z;
    float* xln  = ws + OFF_XLN;
    float* qkv  = ws + OFF_QKV;
    float* atto = ws + OFF_ATTO;
    float* hbuf = ws + OFF_H;
    float* ze   = ws + OFF_ZE;
    float* zq   = ws + OFF_ZQ;
    float* cn   = ws + OFF_CN;
    int*   idxb = (int*)(ws + OFF_IDX);
    float* cnt  = ws + OFF_CNT;
    float* part = ws + OFF_PART;
    float* out  = (float*)d_out;

    hipMemsetAsync(cnt, 0, Kq * sizeof(float), stream);
    cnorm_kernel<<<Kq / 4, 256, 0, stream>>>(cbook, cn);

    // ---- encoder front: patchify -> patch embed (split-K 6, partials in big upper half) ----
    patchify_kernel<<<(int)(((long)TOKq * PINq + 255) / 256), 256, 0, stream>>>(video, big);
    launch_gemm(stream, 0, false, big, PINq, epW, Dq, nullptr, nullptr, nullptr, Dq,
                big + (long)TOKq * PINq, CEXT,
                TOKq, Dq, PINq, 1.0f, 1, 1, 6, 512, 0,0,0,0,0,0,0,0);
    launch_reduce(stream, 0, big + (long)TOKq * PINq, CEXT, 6, epb, Dq, z, CEXT);
    posadd_kernel<<<(int)(((long)TOKq * Dq + 255) / 256), 256, 0, stream>>>(z, ept, ephp, epwp);

    for (int l = 0; l < Lq; ++l)
        block_fwd(stream, z, xln, qkv, big, atto, hbuf, big,
                  eln1s + l * Dq, eln1b + l * Dq,
                  eWqkv + (long)l * 3 * Dq * Dq, ebqkv + l * 3 * Dq,
                  eWo + (long)l * Dq * Dq, ebo + l * Dq,
                  eln2s + l * Dq, eln2b + l * Dq,
                  eW1 + (long)l * Dq * DFFq, eb1 + l * DFFq,
                  eW2 + (long)l * DFFq * Dq, eb2 + l * Dq);

    ln_kernel<<<TOKq / 4, 256, 0, stream>>>(z, elnfs, elnfb, xln, TOKq);
    launch_gemm(stream, 0, false, xln, Dq, ecbW, Dq, nullptr, nullptr, nullptr, Dq, big, CEXT,
                TOKq, Dq, Dq, 1.0f, 1, 1, 2, 256, 0,0,0,0,0,0,0,0);
    launch_reduce(stream, 0, big, CEXT, 2, ecbb, Dq, ze, CEXT);

    // ---- VQ ----
    launch_gemm(stream, 3, true, ze, Dq, cbook, Dq, nullptr, cn, big, Kq, nullptr, 0,
                TOKq, Kq, Dq, 1.0f, 1, 1, 1, Dq, 0,0,0,0,0,0,0,0);
    argmin_kernel<<<TOKq, 256, 0, stream>>>(big, idxb, out + RECN);
    zq_kernel<<<TOKq, 256, 0, stream>>>(cbook, idxb, ze, zq, part, cnt);
    scalars_kernel<<<1, 256, 0, stream>>>(part, cnt, out);

    // ---- decoder ----
    launch_gemm(stream, 0, false, zq, Dq, dcbW, Dq, nullptr, nullptr, nullptr, Dq, big, CEXT,
                TOKq, Dq, Dq, 1.0f, 1, 1, 2, 256, 0,0,0,0,0,0,0,0);
    launch_reduce(stream, 0, big, CEXT, 2, dcbb, Dq, z, CEXT);
    posadd_kernel<<<(int)(((long)TOKq * Dq + 255) / 256), 256, 0, stream>>>(z, dpt, dphp, dpwp);

    for (int l = 0; l < Lq; ++l)
        block_fwd(stream, z, xln, qkv, big, atto, hbuf, big,
                  dln1s + l * Dq, dln1b + l * Dq,
                  dWqkv + (long)l * 3 * Dq * Dq, dbqkv + l * 3 * Dq,
                  dWo + (long)l * Dq * Dq, dbo + l * Dq,
                  dln2s + l * Dq, dln2b + l * Dq,
                  dW1 + (long)l * Dq * DFFq, db1 + l * DFFq,
                  dW2 + (long)l * DFFq * Dq, db2 + l * Dq);

    ln_kernel<<<TOKq / 4, 256, 0, stream>>>(z, dlnfs, dlnfb, xln, TOKq);
    launch_gemm(stream, 0, false, xln, Dq, dpxW, PINq, dpxb, nullptr, big, PINq, nullptr, 0,
                TOKq, PINq, Dq, 1.0f, 1, 1, 1, Dq, 0,0,0,0,0,0,0,0);
    unpatchify_kernel<<<(int)((RECN + 255) / 256), 256, 0, stream>>>(big, out);
}

// Round 3
// 2696.875 us; speedup vs baseline: 2.1713x; 1.1476x over previous
//
#include <hip/hip_runtime.h>
#include <math.h>

// ---- problem dims ----
#define Bq    2
#define Dq    512
#define DFFq  2048
#define Lq    6
#define NHq   8
#define HDq   64
#define Kq    8192
#define Sq    784
#define PINq  3072
#define TOKq  1568
#define RECN  4816896L

// ---- workspace layout (float offsets) ----
#define OFF_BIG  0L
#define SZ_BIG   12845056L
#define OFF_Z    (OFF_BIG + SZ_BIG)
#define OFF_XLN  (OFF_Z    + 802816L)
#define OFF_QKV  (OFF_XLN  + 802816L)
#define OFF_ATTO (OFF_QKV  + 2408448L)
#define OFF_H    (OFF_ATTO + 802816L)
#define OFF_ZE   (OFF_H    + 3211264L)
#define OFF_ZQ   (OFF_ZE   + 802816L)
#define OFF_CN   (OFF_ZQ   + 802816L)
#define OFF_IDX  (OFF_CN   + 8192L)
#define OFF_CNT  (OFF_IDX  + 1568L)
#define OFF_PART (OFF_CNT  + 8192L)
#define OFF_END  (OFF_PART + 1568L)

#define CEXT 802816L

typedef short bf16x8 __attribute__((ext_vector_type(8)));
typedef float f32x4  __attribute__((ext_vector_type(4)));
typedef unsigned short u16;

#define LP 40   // LDS row pitch in u16 (80B rows, 16B aligned)

// plane offsets (u16 elements)
#define XLO 802816L     // xln lo plane
#define QLO 2408448L    // qkv lo plane
#define ALO 802816L     // atto lo plane
#define HLO 3211264L    // hbuf lo plane
#define PLO 4816896L    // patches lo plane
#define ZLO 802816L     // ze_split / zq lo plane
#define CBLO 4194304L   // codebook split lo plane

// ================= helpers =================
__device__ __forceinline__ float wave_sum(float v) {
    #pragma unroll
    for (int o = 32; o; o >>= 1) v += __shfl_xor(v, o);
    return v;
}
__device__ __forceinline__ float wave_max(float v) {
    #pragma unroll
    for (int o = 32; o; o >>= 1) v = fmaxf(v, __shfl_xor(v, o));
    return v;
}
__device__ __forceinline__ float gelu_f(float x) {
    float x3 = x * x * x;
    return 0.5f * x * (1.0f + tanhf(0.7978845608028654f * (x + 0.044715f * x3)));
}
__device__ __forceinline__ void split_f32(float x, u16& h, u16& l) {
    unsigned u = __float_as_uint(x);
    unsigned t = u + 0x7fffu + ((u >> 16) & 1u);
    h = (u16)(t >> 16);
    float r = x - __uint_as_float((t >> 16) << 16);
    l = (u16)(__float_as_uint(r) >> 16);
}

// ================= weight convert+transpose: W[K,N] f32 -> WT[N][K] bf16 hi/lo =================
__global__ __launch_bounds__(256)
void wconv_t(const float* __restrict__ W, int ldw, int Kd,
             u16* __restrict__ WT, long loT, long soW, long soT)
{
    __shared__ u16 Lh[32][33], Ll[32][33];
    const float* Wp = W + (long)blockIdx.z * soW;
    u16* Tp = WT + (long)blockIdx.z * soT;
    int k0 = blockIdx.x << 5, n0 = blockIdx.y << 5;
    int t = threadIdx.x;
    int r = t >> 3, c4 = (t & 7) << 2;
    float4 v = *(const float4*)(Wp + (long)(k0 + r) * ldw + n0 + c4);
    u16 h, l;
    split_f32(v.x, h, l); Lh[c4+0][r] = h; Ll[c4+0][r] = l;
    split_f32(v.y, h, l); Lh[c4+1][r] = h; Ll[c4+1][r] = l;
    split_f32(v.z, h, l); Lh[c4+2][r] = h; Ll[c4+2][r] = l;
    split_f32(v.w, h, l); Lh[c4+3][r] = h; Ll[c4+3][r] = l;
    __syncthreads();
    int n = t >> 3, kc = (t & 7) << 2;
    u16* dst = Tp + (long)(n0 + n) * Kd + k0 + kc;
    u16 oh[4] = {Lh[n][kc], Lh[n][kc+1], Lh[n][kc+2], Lh[n][kc+3]};
    u16 ol[4] = {Ll[n][kc], Ll[n][kc+1], Ll[n][kc+2], Ll[n][kc+3]};
    *(uint2*)dst = *(uint2*)oh;
    *(uint2*)(dst + loT) = *(uint2*)ol;
}

// ================= plain planar split (layout already [N][K]) =================
__global__ __launch_bounds__(256)
void splitp(const float* __restrict__ X, u16* __restrict__ Y, long lo, long n4)
{
    long i = (long)blockIdx.x * 256 + threadIdx.x;
    if (i >= n4) return;
    float4 v = *(const float4*)(X + i * 4);
    u16 h[4], l[4];
    split_f32(v.x, h[0], l[0]); split_f32(v.y, h[1], l[1]);
    split_f32(v.z, h[2], l[2]); split_f32(v.w, h[3], l[3]);
    *(uint2*)(Y + i * 4) = *(uint2*)h;
    *(uint2*)(Y + lo + i * 4) = *(uint2*)l;
}

// ================= MFMA bf16x3 GEMM, pre-split planar inputs =================
// A: [M rows][rsA] u16 hi, lo at +loA.  B (BKN=0): [N][rsB] hi, lo at +loB.
// B (BKN=1): [K][rsB] hi, lo at +loB.
// MATH 0: f32 out = alpha*acc + bias[n]; 2: planar gelu(acc+bias); 3: f32 extra[n]-2acc;
// 4: planar acc+bias.  ksplit>1: raw f32 partials to part.
template<int MATH, bool BKN>
__global__ __launch_bounds__(256)
void gemm_bb(const u16* __restrict__ A, long rsA, long loA, long soA, long siA,
             const u16* __restrict__ B, long rsB, long loB, long soB, long siB,
             const float* __restrict__ bias, long siBias,
             const float* __restrict__ extra,
             float* __restrict__ Cf, int ldc, long soC, long siC,
             u16* __restrict__ Cb, int rsC, long loC,
             float* __restrict__ part, long pstride,
             int M, int N, int K, float alpha,
             int bdiv, int ksplit, int klen)
{
    __shared__ u16 Ah[64 * LP], Al[64 * LP], Bh[64 * LP], Bl[64 * LP];
    const int zb2 = blockIdx.z;
    const int zk = zb2 % ksplit, zb = zb2 / ksplit;
    const int zo = zb / bdiv, zi = zb - zo * bdiv;
    A += zo * soA + zi * siA;
    B += zo * soB + zi * siB;
    const float* bi = bias ? bias + zi * siBias : nullptr;

    const int t = threadIdx.x;
    const int m0 = blockIdx.x << 6, n0 = blockIdx.y << 6;
    const int kbeg = zk * klen;
    int kend = kbeg + klen; if (kend > K) kend = K;

    const int w = t >> 6, lane = t & 63;
    const int wm = w >> 1, wn = w & 1;
    const int l15 = lane & 15, lk = (lane >> 4) << 3;
    const int ar = t >> 2, ac = (t & 3) << 3;
    const int kr = t >> 3, nc = (t & 7) << 3;

    int grA = m0 + ar; if (grA > M - 1) grA = M - 1;
    const u16* Apr = A + (long)grA * rsA;
    int grB = n0 + ar; if (grB > N - 1) grB = N - 1;
    const u16* Bpr = B + (long)grB * rsB;

    f32x4 acc[2][2] = {};

    for (int k0 = kbeg; k0 < kend; k0 += 32) {
        {
            int ka = k0 + ac;
            uint4 vh = {0,0,0,0}, vl = {0,0,0,0};
            if (ka + 8 <= kend) { vh = *(const uint4*)(Apr + ka); vl = *(const uint4*)(Apr + ka + loA); }
            *(uint4*)&Ah[ar * LP + ac] = vh;
            *(uint4*)&Al[ar * LP + ac] = vl;
        }
        if (!BKN) {
            int ka = k0 + ac;
            uint4 vh = {0,0,0,0}, vl = {0,0,0,0};
            if (ka + 8 <= kend) { vh = *(const uint4*)(Bpr + ka); vl = *(const uint4*)(Bpr + ka + loB); }
            *(uint4*)&Bh[ar * LP + ac] = vh;
            *(uint4*)&Bl[ar * LP + ac] = vl;
        } else {
            int kb = k0 + kr;
            uint4 vh = {0,0,0,0}, vl = {0,0,0,0};
            if (kb < kend) {
                const u16* Bp = B + (long)kb * rsB + n0 + nc;
                vh = *(const uint4*)Bp; vl = *(const uint4*)(Bp + loB);
            }
            const u16* ph = (const u16*)&vh; const u16* pl = (const u16*)&vl;
            #pragma unroll
            for (int j = 0; j < 8; ++j) {
                Bh[(nc + j) * LP + kr] = ph[j];
                Bl[(nc + j) * LP + kr] = pl[j];
            }
        }
        __syncthreads();

        bf16x8 ah[2], al2[2], bh2[2], bl2[2];
        #pragma unroll
        for (int mi = 0; mi < 2; ++mi) {
            int row = (wm << 5) + (mi << 4) + l15;
            ah[mi]  = *(const bf16x8*)&Ah[row * LP + lk];
            al2[mi] = *(const bf16x8*)&Al[row * LP + lk];
        }
        #pragma unroll
        for (int ni = 0; ni < 2; ++ni) {
            int row = (wn << 5) + (ni << 4) + l15;
            bh2[ni] = *(const bf16x8*)&Bh[row * LP + lk];
            bl2[ni] = *(const bf16x8*)&Bl[row * LP + lk];
        }
        #pragma unroll
        for (int mi = 0; mi < 2; ++mi)
            #pragma unroll
            for (int ni = 0; ni < 2; ++ni) {
                acc[mi][ni] = __builtin_amdgcn_mfma_f32_16x16x32_bf16(ah[mi],  bh2[ni], acc[mi][ni], 0, 0, 0);
                acc[mi][ni] = __builtin_amdgcn_mfma_f32_16x16x32_bf16(ah[mi],  bl2[ni], acc[mi][ni], 0, 0, 0);
                acc[mi][ni] = __builtin_amdgcn_mfma_f32_16x16x32_bf16(al2[mi], bh2[ni], acc[mi][ni], 0, 0, 0);
            }
        __syncthreads();
    }

    if (ksplit > 1) {
        float* P = part + (long)zk * pstride + zo * soC + zi * siC;
        #pragma unroll
        for (int mi = 0; mi < 2; ++mi)
            #pragma unroll
            for (int ni = 0; ni < 2; ++ni) {
                int gn = n0 + (wn << 5) + (ni << 4) + l15;
                if (gn >= N) continue;
                int gmb = m0 + (wm << 5) + (mi << 4) + ((lane >> 4) << 2);
                #pragma unroll
                for (int r = 0; r < 4; ++r) {
                    int gm = gmb + r;
                    if (gm < M) P[(long)gm * ldc + gn] = acc[mi][ni][r];
                }
            }
        return;
    }
    if (MATH == 0 || MATH == 3) {
        float* Co = Cf + zo * soC + zi * siC;
        #pragma unroll
        for (int mi = 0; mi < 2; ++mi)
            #pragma unroll
            for (int ni = 0; ni < 2; ++ni) {
                int gn = n0 + (wn << 5) + (ni << 4) + l15;
                if (gn >= N) continue;
                int gmb = m0 + (wm << 5) + (mi << 4) + ((lane >> 4) << 2);
                #pragma unroll
                for (int r = 0; r < 4; ++r) {
                    int gm = gmb + r;
                    if (gm >= M) continue;
                    float v = acc[mi][ni][r];
                    if (MATH == 0) v = alpha * v + (bi ? bi[gn] : 0.0f);
                    else           v = extra[gn] - 2.0f * v;
                    Co[(long)gm * ldc + gn] = v;
                }
            }
    } else {
        u16* Cu = Cb + zo * soC + zi * siC;
        #pragma unroll
        for (int mi = 0; mi < 2; ++mi)
            #pragma unroll
            for (int ni = 0; ni < 2; ++ni) {
                int gn = n0 + (wn << 5) + (ni << 4) + l15;
                if (gn >= N) continue;
                int gmb = m0 + (wm << 5) + (mi << 4) + ((lane >> 4) << 2);
                #pragma unroll
                for (int r = 0; r < 4; ++r) {
                    int gm = gmb + r;
                    if (gm >= M) continue;
                    float v = acc[mi][ni][r] + bi[gn];
                    if (MATH == 2) v = gelu_f(v);
                    u16 h, l; split_f32(v, h, l);
                    Cu[(long)gm * rsC + gn] = h;
                    Cu[(long)gm * rsC + gn + loC] = l;
                }
            }
    }
}

// ================= split-K reduce =================
// 0: Cf=s+b; 1: Cf+=s+b; 2: planar(s+b); 3: Cf=s+b AND planar
template<int MATH>
__global__ __launch_bounds__(256)
void reduce_k(const float* __restrict__ part, long pstride, int ks,
              const float* __restrict__ bias, int ldc,
              float* __restrict__ Cf, u16* __restrict__ Cb, long loC, long total)
{
    long i = (long)blockIdx.x * 256 + threadIdx.x;
    if (i >= total) return;
    float s = 0.f;
    for (int k = 0; k < ks; ++k) s += part[(long)k * pstride + i];
    int col = (int)(i % ldc);
    float b = bias ? bias[col] : 0.0f;
    float v = s + b;
    if (MATH == 0) Cf[i] = v;
    else if (MATH == 1) Cf[i] += v;
    else if (MATH == 2) { u16 h, l; split_f32(v, h, l); Cb[i] = h; Cb[i + loC] = l; }
    else { Cf[i] = v; u16 h, l; split_f32(v, h, l); Cb[i] = h; Cb[i + loC] = l; }
}

// ================= LayerNorm -> planar bf16 =================
__global__ __launch_bounds__(256)
void ln_kernel(const float* __restrict__ x, const float* __restrict__ s,
               const float* __restrict__ b, u16* __restrict__ y, long lo, int rows)
{
    int wave = threadIdx.x >> 6, lane = threadIdx.x & 63;
    int row = (blockIdx.x << 2) + wave;
    if (row >= rows) return;
    const float* xr = x + (long)row * Dq;
    float4 v0 = *(const float4*)(xr + (lane << 2));
    float4 v1 = *(const float4*)(xr + 256 + (lane << 2));
    float sum = v0.x+v0.y+v0.z+v0.w + v1.x+v1.y+v1.z+v1.w;
    sum = wave_sum(sum);
    float m = sum * (1.0f / 512.0f);
    float d0x=v0.x-m,d0y=v0.y-m,d0z=v0.z-m,d0w=v0.w-m;
    float d1x=v1.x-m,d1y=v1.y-m,d1z=v1.z-m,d1w=v1.w-m;
    float vs = d0x*d0x+d0y*d0y+d0z*d0z+d0w*d0w + d1x*d1x+d1y*d1y+d1z*d1z+d1w*d1w;
    vs = wave_sum(vs);
    float rstd = 1.0f / sqrtf(vs * (1.0f / 512.0f) + 1e-6f);
    int c0 = lane << 2;
    u16 h0[4], l0[4], h1[4], l1[4];
    split_f32(d0x*rstd*s[c0+0]+b[c0+0], h0[0], l0[0]);
    split_f32(d0y*rstd*s[c0+1]+b[c0+1], h0[1], l0[1]);
    split_f32(d0z*rstd*s[c0+2]+b[c0+2], h0[2], l0[2]);
    split_f32(d0w*rstd*s[c0+3]+b[c0+3], h0[3], l0[3]);
    split_f32(d1x*rstd*s[256+c0+0]+b[256+c0+0], h1[0], l1[0]);
    split_f32(d1y*rstd*s[256+c0+1]+b[256+c0+1], h1[1], l1[1]);
    split_f32(d1z*rstd*s[256+c0+2]+b[256+c0+2], h1[2], l1[2]);
    split_f32(d1w*rstd*s[256+c0+3]+b[256+c0+3], h1[3], l1[3]);
    u16* yr = y + (long)row * Dq;
    *(uint2*)(yr + c0)            = *(uint2*)h0;
    *(uint2*)(yr + lo + c0)       = *(uint2*)l0;
    *(uint2*)(yr + 256 + c0)      = *(uint2*)h1;
    *(uint2*)(yr + lo + 256 + c0) = *(uint2*)l1;
}

// ================= softmax: f32 in, row-interleaved bf16 hi/lo out (in place) =================
__global__ __launch_bounds__(256)
void softmax_kernel(float* __restrict__ att, int rows, int n)
{
    int wave = threadIdx.x >> 6, lane = threadIdx.x & 63;
    int row = (blockIdx.x << 2) + wave;
    if (row >= rows) return;
    float* a = att + (long)row * n;
    float e[13];
    float mx = -1e30f;
    #pragma unroll
    for (int i = 0; i < 13; ++i) {
        int c = lane + (i << 6);
        if (c < n) { e[i] = a[c]; mx = fmaxf(mx, e[i]); }
        else e[i] = -1e30f;
    }
    mx = wave_max(mx);
    float ssum = 0.f;
    #pragma unroll
    for (int i = 0; i < 13; ++i) {
        int c = lane + (i << 6);
        if (c < n) { e[i] = expf(e[i] - mx); ssum += e[i]; }
    }
    ssum = wave_sum(ssum);
    u16* rowp = (u16*)att + (long)row * (2 * n);
    #pragma unroll
    for (int i = 0; i < 13; ++i) {
        int c = lane + (i << 6);
        if (c < n) {
            u16 h, l; split_f32(e[i] / ssum, h, l);
            rowp[c] = h; rowp[n + c] = l;
        }
    }
}

// ================= codebook norms =================
__global__ __launch_bounds__(256)
void cnorm_kernel(const float* __restrict__ cb, float* __restrict__ cn)
{
    int wave = threadIdx.x >> 6, lane = threadIdx.x & 63;
    int row = (blockIdx.x << 2) + wave;
    if (row >= Kq) return;
    const float* cr = cb + (long)row * Dq;
    float4 v0 = *(const float4*)(cr + (lane << 2));
    float4 v1 = *(const float4*)(cr + 256 + (lane << 2));
    float ss = v0.x*v0.x+v0.y*v0.y+v0.z*v0.z+v0.w*v0.w
             + v1.x*v1.x+v1.y*v1.y+v1.z*v1.z+v1.w*v1.w;
    ss = wave_sum(ss);
    if (lane == 0) cn[row] = ss;
}

// ================= patchify (planar bf16 out) / unpatchify / posadd =================
__global__ void patchify_kernel(const float* __restrict__ video, u16* __restrict__ patches)
{
    long i = (long)blockIdx.x * 256 + threadIdx.x;
    if (i >= (long)TOKq * PINq) return;
    int row = (int)(i / PINq), col = (int)(i - (long)row * PINq);
    int c = col % 3; int q = col / 3;
    int pw = q & 15; q >>= 4;
    int ph = q & 15; int tpin = q >> 4;
    int wp = row % 14; int r2 = row / 14;
    int hp = r2 % 14; r2 /= 14;
    int tp = r2 & 3; int b = r2 >> 2;
    int tt = tp * 4 + tpin;
    int ih = hp * 16 + ph, iw = wp * 16 + pw;
    float v = video[(((long)(b * 16 + tt) * 224 + ih) * 224 + iw) * 3 + c];
    u16 h, l; split_f32(v, h, l);
    patches[i] = h; patches[PLO + i] = l;
}

__global__ void unpatchify_kernel(const float* __restrict__ px, float* __restrict__ out)
{
    long o = (long)blockIdx.x * 256 + threadIdx.x;
    if (o >= RECN) return;
    int c = (int)(o % 3); long r = o / 3;
    int iw = (int)(r % 224); r /= 224;
    int ih = (int)(r % 224); r /= 224;
    int tt = (int)(r % 16); int b = (int)(r / 16);
    int tp = tt >> 2, tpin = tt & 3;
    int hp = ih >> 4, ph = ih & 15;
    int wp = iw >> 4, pw = iw & 15;
    long prow = ((long)(b * 4 + tp) * 14 + hp) * 14 + wp;
    int pcol = ((tpin * 16 + ph) * 16 + pw) * 3 + c;
    out[o] = px[prow * PINq + pcol];
}

__global__ void posadd_kernel(float* __restrict__ z, const float* __restrict__ pt,
                              const float* __restrict__ ph, const float* __restrict__ pw)
{
    long i = (long)blockIdx.x * 256 + threadIdx.x;
    if (i >= (long)TOKq * Dq) return;
    int d = (int)(i & 511); long r = i >> 9;
    int w = (int)(r % 14); r /= 14;
    int hh = (int)(r % 14); r /= 14;
    int tp = (int)(r & 3);
    z[i] += pt[tp * Dq + d] + ph[hh * Dq + d] + pw[w * Dq + d];
}

// ================= VQ argmin =================
__global__ __launch_bounds__(256)
void argmin_kernel(const float* __restrict__ d2, int* __restrict__ idxb, float* __restrict__ out_idx)
{
    int tok = blockIdx.x;
    const float* r = d2 + (long)tok * Kq;
    float bv = 1e30f; int bi = 0x7fffffff;
    for (int k = threadIdx.x; k < Kq; k += 256) {
        float v = r[k];
        if (v < bv) { bv = v; bi = k; }
    }
    __shared__ float sv[256];
    __shared__ int   si[256];
    sv[threadIdx.x] = bv; si[threadIdx.x] = bi;
    __syncthreads();
    for (int s2 = 128; s2; s2 >>= 1) {
        if (threadIdx.x < s2) {
            float ov = sv[threadIdx.x + s2]; int oi = si[threadIdx.x + s2];
            if (ov < sv[threadIdx.x] || (ov == sv[threadIdx.x] && oi < si[threadIdx.x])) {
                sv[threadIdx.x] = ov; si[threadIdx.x] = oi;
            }
        }
        __syncthreads();
    }
    if (threadIdx.x == 0) { idxb[tok] = si[0]; out_idx[tok] = (float)si[0]; }
}

// ================= z_q gather -> planar bf16 + SSE + counts =================
__global__ __launch_bounds__(256)
void zq_kernel(const float* __restrict__ cb, const int* __restrict__ idxb,
               const float* __restrict__ ze, u16* __restrict__ zqp, long lo,
               float* __restrict__ part, float* __restrict__ counts)
{
    int tok = blockIdx.x;
    int id = idxb[tok];
    const float* c = cb + (long)id * Dq;
    const float* z = ze + (long)tok * Dq;
    float ss = 0.f;
    for (int d = threadIdx.x; d < Dq; d += 256) {
        float cv = c[d];
        u16 h, l; split_f32(cv, h, l);
        zqp[(long)tok * Dq + d] = h;
        zqp[lo + (long)tok * Dq + d] = l;
        float df = cv - z[d];
        ss += df * df;
    }
    float wsum = wave_sum(ss);
    __shared__ float sw[4];
    if ((threadIdx.x & 63) == 0) sw[threadIdx.x >> 6] = wsum;
    __syncthreads();
    if (threadIdx.x == 0) {
        part[tok] = sw[0] + sw[1] + sw[2] + sw[3];
        atomicAdd(&counts[id], 1.0f);
    }
}

// ================= scalars =================
__global__ __launch_bounds__(256)
void scalars_kernel(const float* __restrict__ part, const float* __restrict__ counts,
                    float* __restrict__ out)
{
    float se = 0.f;
    for (int t = threadIdx.x; t < TOKq; t += 256) se += part[t];
    float pl = 0.f;
    for (int k = threadIdx.x; k < Kq; k += 256) {
        float p = counts[k] * (1.0f / 1568.0f);
        pl += p * logf(p + 1e-10f);
    }
    float wse = wave_sum(se), wpl = wave_sum(pl);
    __shared__ float s1[4], s2[4];
    if ((threadIdx.x & 63) == 0) { s1[threadIdx.x >> 6] = wse; s2[threadIdx.x >> 6] = wpl; }
    __syncthreads();
    if (threadIdx.x == 0) {
        float sse = s1[0] + s1[1] + s1[2] + s1[3];
        float plo = s2[0] + s2[1] + s2[2] + s2[3];
        float commit = sse / 802816.0f;
        out[RECN + 1568 + 0] = commit;
        out[RECN + 1568 + 1] = commit;
        out[RECN + 1568 + 2] = expf(-plo);
    }
}

// ================= transformer block =================
static void block_fwd(hipStream_t st, float* z, float* big, float* hbuf,
                      u16* xlnu, u16* qkvu, u16* attou, u16* hbu, u16* wscr,
                      const float* ln1s, const float* ln1b,
                      const float* Wqkv, const float* bqkv,
                      const float* Wo, const float* bo,
                      const float* ln2s, const float* ln2b,
                      const float* W1, const float* b1,
                      const float* W2, const float* b2)
{
    u16* attu = (u16*)big;
    ln_kernel<<<TOKq / 4, 256, 0, st>>>(z, ln1s, ln1b, xlnu, XLO, TOKq);
    // Wqkv -> WT [3][512][512], lo at +786432
    wconv_t<<<dim3(16, 16, 3), 256, 0, st>>>(Wqkv, Dq, Dq, wscr, 786432, 262144L, 262144L);
    // qkv = xln @ Wqkv + b  -> planar bf16 into qkv buffer
    gemm_bb<4, false><<<dim3(25, 8, 3), 256, 0, st>>>(
        xlnu, Dq, XLO, 0, 0,
        wscr, Dq, 786432, 0, 262144,
        bqkv, 512, nullptr,
        nullptr, 0, 0, 512,
        qkvu, 3 * Dq, QLO,
        nullptr, 0,
        TOKq, Dq, Dq, 1.0f, 3, 1, Dq);
    // scores = q k^T / 8  (f32 into big)
    gemm_bb<0, false><<<dim3(13, 13, 16), 256, 0, st>>>(
        qkvu, 3 * Dq, QLO, 784L * 1536, 64,
        qkvu + 512, 3 * Dq, QLO, 784L * 1536, 64,
        nullptr, 0, nullptr,
        big, Sq, 8L * 784 * 784, 784L * 784,
        nullptr, 0, 0,
        nullptr, 0,
        Sq, Sq, HDq, 0.125f, NHq, 1, HDq);
    softmax_kernel<<<(Bq * NHq * Sq) / 4, 256, 0, st>>>(big, Bq * NHq * Sq, Sq);
    // o = att @ v  (split-K 4, partials in hbuf) -> atto planar
    gemm_bb<0, true><<<dim3(13, 1, 64), 256, 0, st>>>(
        attu, 2 * Sq, Sq, 8L * 784 * 1568, 784L * 1568,
        qkvu + 1024, 3 * Dq, QLO, 784L * 1536, 64,
        nullptr, 0, nullptr,
        nullptr, Dq, 784L * 512, 64,
        nullptr, 0, 0,
        hbuf, CEXT,
        Sq, HDq, Sq, 1.0f, NHq, 4, 224);
    reduce_k<2><<<(CEXT + 255) / 256, 256, 0, st>>>(hbuf, CEXT, 4, nullptr, Dq, nullptr, attou, ALO, CEXT);
    // z += atto @ Wo + bo
    wconv_t<<<dim3(16, 16, 1), 256, 0, st>>>(Wo, Dq, Dq, wscr, 262144, 0, 0);
    gemm_bb<0, false><<<dim3(25, 8, 4), 256, 0, st>>>(
        attou, Dq, ALO, 0, 0,
        wscr, Dq, 262144, 0, 0,
        nullptr, 0, nullptr,
        nullptr, Dq, 0, 0,
        nullptr, 0, 0,
        hbuf, CEXT,
        TOKq, Dq, Dq, 1.0f, 1, 4, 128);
    reduce_k<1><<<(CEXT + 255) / 256, 256, 0, st>>>(hbuf, CEXT, 4, bo, Dq, z, nullptr, 0, CEXT);
    // FFN
    ln_kernel<<<TOKq / 4, 256, 0, st>>>(z, ln2s, ln2b, xlnu, XLO, TOKq);
    wconv_t<<<dim3(16, 64, 1), 256, 0, st>>>(W1, DFFq, Dq, wscr, 1048576, 0, 0);
    gemm_bb<2, false><<<dim3(25, 32, 1), 256, 0, st>>>(
        xlnu, Dq, XLO, 0, 0,
        wscr, Dq, 1048576, 0, 0,
        b1, 0, nullptr,
        nullptr, 0, 0, 0,
        hbu, DFFq, HLO,
        nullptr, 0,
        TOKq, DFFq, Dq, 1.0f, 1, 1, Dq);
    wconv_t<<<dim3(64, 16, 1), 256, 0, st>>>(W2, Dq, DFFq, wscr, 1048576, 0, 0);
    gemm_bb<0, false><<<dim3(25, 8, 4), 256, 0, st>>>(
        hbu, DFFq, HLO, 0, 0,
        wscr, DFFq, 1048576, 0, 0,
        nullptr, 0, nullptr,
        nullptr, Dq, 0, 0,
        nullptr, 0, 0,
        big, CEXT,
        TOKq, Dq, DFFq, 1.0f, 1, 4, 512);
    reduce_k<1><<<(CEXT + 255) / 256, 256, 0, st>>>(big, CEXT, 4, b2, Dq, z, nullptr, 0, CEXT);
}

extern "C" void kernel_launch(void* const* d_in, const int* in_sizes, int n_in,
                              void* d_out, int out_size, void* d_ws, size_t ws_size,
                              hipStream_t stream)
{
    (void)in_sizes; (void)n_in; (void)out_size;
    if (ws_size < (size_t)OFF_END * sizeof(float)) return;

    const float* video = (const float*)d_in[0];
    const float* epW   = (const float*)d_in[1];  const float* epb   = (const float*)d_in[2];
    const float* ept   = (const float*)d_in[3];  const float* ephp  = (const float*)d_in[4];
    const float* epwp  = (const float*)d_in[5];
    const float* eln1s = (const float*)d_in[6];  const float* eln1b = (const float*)d_in[7];
    const float* eWqkv = (const float*)d_in[8];  const float* ebqkv = (const float*)d_in[9];
    const float* eWo   = (const float*)d_in[10]; const float* ebo   = (const float*)d_in[11];
    const float* eln2s = (const float*)d_in[12]; const float* eln2b = (const float*)d_in[13];
    const float* eW1   = (const float*)d_in[14]; const float* eb1   = (const float*)d_in[15];
    const float* eW2   = (const float*)d_in[16]; const float* eb2   = (const float*)d_in[17];
    const float* elnfs = (const float*)d_in[18]; const float* elnfb = (const float*)d_in[19];
    const float* ecbW  = (const float*)d_in[20]; const float* ecbb  = (const float*)d_in[21];
    const float* cbook = (const float*)d_in[22];
    const float* dcbW  = (const float*)d_in[23]; const float* dcbb  = (const float*)d_in[24];
    const float* dpt   = (const float*)d_in[25]; const float* dphp  = (const float*)d_in[26];
    const float* dpwp  = (const float*)d_in[27];
    const float* dln1s = (const float*)d_in[28]; const float* dln1b = (const float*)d_in[29];
    const float* dWqkv = (const float*)d_in[30]; const float* dbqkv = (const float*)d_in[31];
    const float* dWo   = (const float*)d_in[32]; const float* dbo   = (const float*)d_in[33];
    const float* dln2s = (const float*)d_in[34]; const float* dln2b = (const float*)d_in[35];
    const float* dW1   = (const float*)d_in[36]; const float* db1   = (const float*)d_in[37];
    const float* dW2   = (const float*)d_in[38]; const float* db2   = (const float*)d_in[39];
    const float* dlnfs = (const float*)d_in[40]; const float* dlnfb = (const float*)d_in[41];
    const float* dpxW  = (const float*)d_in[42]; const float* dpxb  = (const float*)d_in[43];

    float* ws   = (float*)d_ws;
    float* big  = ws + OFF_BIG;
    float* z    = ws + OFF_Z;
    float* xln  = ws + OFF_XLN;
    float* qkv  = ws + OFF_QKV;
    float* atto = ws + OFF_ATTO;
    float* hbuf = ws + OFF_H;
    float* ze   = ws + OFF_ZE;
    float* zq   = ws + OFF_ZQ;
    float* cn   = ws + OFF_CN;
    int*   idxb = (int*)(ws + OFF_IDX);
    float* cnt  = ws + OFF_CNT;
    float* part = ws + OFF_PART;
    float* out  = (float*)d_out;

    u16* xlnu  = (u16*)xln;
    u16* qkvu  = (u16*)qkv;
    u16* attou = (u16*)atto;
    u16* hbu   = (u16*)hbuf;
    u16* patu  = (u16*)big;
    u16* zqu   = (u16*)zq;       // ze_split, then zq planar
    u16* cbs   = (u16*)qkv;      // codebook split (qkv+atto region, dead during VQ)
    u16* wscr  = (u16*)(big + 10485760);

    hipMemsetAsync(cnt, 0, Kq * sizeof(float), stream);
    cnorm_kernel<<<Kq / 4, 256, 0, stream>>>(cbook, cn);

    // ---- encoder front ----
    patchify_kernel<<<(int)(((long)TOKq * PINq + 255) / 256), 256, 0, stream>>>(video, patu);
    wconv_t<<<dim3(96, 16, 1), 256, 0, stream>>>(epW, Dq, PINq, wscr, 1572864, 0, 0);
    gemm_bb<0, false><<<dim3(25, 8, 6), 256, 0, stream>>>(
        patu, PINq, PLO, 0, 0,
        wscr, PINq, 1572864, 0, 0,
        nullptr, 0, nullptr,
        nullptr, Dq, 0, 0,
        nullptr, 0, 0,
        big + PLO, CEXT,
        TOKq, Dq, PINq, 1.0f, 1, 6, 512);
    reduce_k<0><<<(CEXT + 255) / 256, 256, 0, stream>>>(big + PLO, CEXT, 6, epb, Dq, z, nullptr, 0, CEXT);
    posadd_kernel<<<(int)(((long)TOKq * Dq + 255) / 256), 256, 0, stream>>>(z, ept, ephp, epwp);

    for (int l = 0; l < Lq; ++l)
        block_fwd(stream, z, big, hbuf, xlnu, qkvu, attou, hbu, wscr,
                  eln1s + l * Dq, eln1b + l * Dq,
                  eWqkv + (long)l * 3 * Dq * Dq, ebqkv + l * 3 * Dq,
                  eWo + (long)l * Dq * Dq, ebo + l * Dq,
                  eln2s + l * Dq, eln2b + l * Dq,
                  eW1 + (long)l * Dq * DFFq, eb1 + l * DFFq,
                  eW2 + (long)l * DFFq * Dq, eb2 + l * Dq);

    // ---- encoder head: ze = lnf(z) @ ecbW + b ----
    ln_kernel<<<TOKq / 4, 256, 0, stream>>>(z, elnfs, elnfb, xlnu, XLO, TOKq);
    wconv_t<<<dim3(16, 16, 1), 256, 0, stream>>>(ecbW, Dq, Dq, wscr, 262144, 0, 0);
    gemm_bb<0, false><<<dim3(25, 8, 2), 256, 0, stream>>>(
        xlnu, Dq, XLO, 0, 0,
        wscr, Dq, 262144, 0, 0,
        nullptr, 0, nullptr,
        nullptr, Dq, 0, 0,
        nullptr, 0, 0,
        big, CEXT,
        TOKq, Dq, Dq, 1.0f, 1, 2, 256);
    reduce_k<3><<<(CEXT + 255) / 256, 256, 0, stream>>>(big, CEXT, 2, ecbb, Dq, ze, zqu, ZLO, CEXT);

    // ---- VQ ----
    splitp<<<(int)(((long)Kq * Dq / 4 + 255) / 256), 256, 0, stream>>>(cbook, cbs, CBLO, (long)Kq * Dq / 4);
    gemm_bb<3, false><<<dim3(25, 128, 1), 256, 0, stream>>>(
        zqu, Dq, ZLO, 0, 0,
        cbs, Dq, CBLO, 0, 0,
        nullptr, 0, cn,
        big, Kq, 0, 0,
        nullptr, 0, 0,
        nullptr, 0,
        TOKq, Kq, Dq, 1.0f, 1, 1, Dq);
    argmin_kernel<<<TOKq, 256, 0, stream>>>(big, idxb, out + RECN);
    zq_kernel<<<TOKq, 256, 0, stream>>>(cbook, idxb, ze, zqu, ZLO, part, cnt);
    scalars_kernel<<<1, 256, 0, stream>>>(part, cnt, out);

    // ---- decoder front ----
    wconv_t<<<dim3(16, 16, 1), 256, 0, stream>>>(dcbW, Dq, Dq, wscr, 262144, 0, 0);
    gemm_bb<0, false><<<dim3(25, 8, 2), 256, 0, stream>>>(
        zqu, Dq, ZLO, 0, 0,
        wscr, Dq, 262144, 0, 0,
        nullptr, 0, nullptr,
        nullptr, Dq, 0, 0,
        nullptr, 0, 0,
        big, CEXT,
        TOKq, Dq, Dq, 1.0f, 1, 2, 256);
    reduce_k<0><<<(CEXT + 255) / 256, 256, 0, stream>>>(big, CEXT, 2, dcbb, Dq, z, nullptr, 0, CEXT);
    posadd_kernel<<<(int)(((long)TOKq * Dq + 255) / 256), 256, 0, stream>>>(z, dpt, dphp, dpwp);

    for (int l = 0; l < Lq; ++l)
        block_fwd(stream, z, big, hbuf, xlnu, qkvu, attou, hbu, wscr,
                  dln1s + l * Dq, dln1b + l * Dq,
                  dWqkv + (long)l * 3 * Dq * Dq, dbqkv + l * 3 * Dq,
                  dWo + (long)l * Dq * Dq, dbo + l * Dq,
                  dln2s + l * Dq, dln2b + l * Dq,
                  dW1 + (long)l * Dq * DFFq, db1 + l * DFFq,
                  dW2 + (long)l * DFFq * Dq, db2 + l * Dq);

    // ---- decoder head: px ----
    ln_kernel<<<TOKq / 4, 256, 0, stream>>>(z, dlnfs, dlnfb, xlnu, XLO, TOKq);
    wconv_t<<<dim3(16, 96, 1), 256, 0, stream>>>(dpxW, PINq, Dq, wscr, 1572864, 0, 0);
    gemm_bb<0, false><<<dim3(25, 48, 1), 256, 0, stream>>>(
        xlnu, Dq, XLO, 0, 0,
        wscr, Dq, 1572864, 0, 0,
        dpxb, 0, nullptr,
        big, PINq, 0, 0,
        nullptr, 0, 0,
        nullptr, 0,
        TOKq, PINq, Dq, 1.0f, 1, 1, Dq);
    unpatchify_kernel<<<(int)((RECN + 255) / 256), 256, 0, stream>>>(big, out);
}

// Round 4
// 2531.088 us; speedup vs baseline: 2.3135x; 1.0655x over previous
//
#include <hip/hip_runtime.h>
#include <math.h>

// ---- problem dims ----
#define Bq    2
#define Dq    512
#define DFFq  2048
#define Lq    6
#define NHq   8
#define HDq   64
#define Kq    8192
#define Sq    784
#define PINq  3072
#define TOKq  1568
#define RECN  4816896L

// ---- workspace layout (float offsets) ----
#define OFF_BIG  0L
#define SZ_BIG   12845056L
#define OFF_Z    (OFF_BIG + SZ_BIG)
#define OFF_XLN  (OFF_Z    + 802816L)
#define OFF_QKV  (OFF_XLN  + 802816L)
#define OFF_ATTO (OFF_QKV  + 2408448L)
#define OFF_H    (OFF_ATTO + 802816L)
#define OFF_ZE   (OFF_H    + 3211264L)
#define OFF_ZQ   (OFF_ZE   + 802816L)
#define OFF_CN   (OFF_ZQ   + 802816L)
#define OFF_IDX  (OFF_CN   + 8192L)
#define OFF_CNT  (OFF_IDX  + 1568L)
#define OFF_PART (OFF_CNT  + 8192L)
#define OFF_MIN  (OFF_PART + 1568L)
#define OFF_END  (OFF_MIN  + 3136L)

#define CEXT 802816L

typedef short bf16x8 __attribute__((ext_vector_type(8)));
typedef float f32x4  __attribute__((ext_vector_type(4)));
typedef unsigned short u16;
typedef unsigned long long u64;

#define LP 40   // GEMM LDS row pitch in u16

// plane offsets (u16 elements)
#define XLO 802816L     // xln lo plane
#define QLO 2408448L    // qkv lo plane
#define ALO 802816L     // atto lo plane
#define HLO 3211264L    // hbuf lo plane
#define PLO 4816896L    // patches lo plane
#define ZLO 802816L     // ze_split / zq lo plane
#define CBLO 4194304L   // codebook split lo plane

// ================= helpers =================
__device__ __forceinline__ float wave_sum(float v) {
    #pragma unroll
    for (int o = 32; o; o >>= 1) v += __shfl_xor(v, o);
    return v;
}
__device__ __forceinline__ float gelu_f(float x) {
    float x3 = x * x * x;
    return 0.5f * x * (1.0f + tanhf(0.7978845608028654f * (x + 0.044715f * x3)));
}
__device__ __forceinline__ void split_f32(float x, u16& h, u16& l) {
    unsigned u = __float_as_uint(x);
    unsigned t = u + 0x7fffu + ((u >> 16) & 1u);
    h = (u16)(t >> 16);
    float r = x - __uint_as_float((t >> 16) << 16);
    l = (u16)(__float_as_uint(r) >> 16);
}

// ================= weight convert+transpose: W[K,N] f32 -> WT[N][K] bf16 hi/lo =================
__global__ __launch_bounds__(256)
void wconv_t(const float* __restrict__ W, int ldw, int Kd,
             u16* __restrict__ WT, long loT, long soW, long soT)
{
    __shared__ u16 Lh[32][33], Ll[32][33];
    const float* Wp = W + (long)blockIdx.z * soW;
    u16* Tp = WT + (long)blockIdx.z * soT;
    int k0 = blockIdx.x << 5, n0 = blockIdx.y << 5;
    int t = threadIdx.x;
    int r = t >> 3, c4 = (t & 7) << 2;
    float4 v = *(const float4*)(Wp + (long)(k0 + r) * ldw + n0 + c4);
    u16 h, l;
    split_f32(v.x, h, l); Lh[c4+0][r] = h; Ll[c4+0][r] = l;
    split_f32(v.y, h, l); Lh[c4+1][r] = h; Ll[c4+1][r] = l;
    split_f32(v.z, h, l); Lh[c4+2][r] = h; Ll[c4+2][r] = l;
    split_f32(v.w, h, l); Lh[c4+3][r] = h; Ll[c4+3][r] = l;
    __syncthreads();
    int n = t >> 3, kc = (t & 7) << 2;
    u16* dst = Tp + (long)(n0 + n) * Kd + k0 + kc;
    u16 oh[4] = {Lh[n][kc], Lh[n][kc+1], Lh[n][kc+2], Lh[n][kc+3]};
    u16 ol[4] = {Ll[n][kc], Ll[n][kc+1], Ll[n][kc+2], Ll[n][kc+3]};
    *(uint2*)dst = *(uint2*)oh;
    *(uint2*)(dst + loT) = *(uint2*)ol;
}

// ================= plain planar split =================
__global__ __launch_bounds__(256)
void splitp(const float* __restrict__ X, u16* __restrict__ Y, long lo, long n4)
{
    long i = (long)blockIdx.x * 256 + threadIdx.x;
    if (i >= n4) return;
    float4 v = *(const float4*)(X + i * 4);
    u16 h[4], l[4];
    split_f32(v.x, h[0], l[0]); split_f32(v.y, h[1], l[1]);
    split_f32(v.z, h[2], l[2]); split_f32(v.w, h[3], l[3]);
    *(uint2*)(Y + i * 4) = *(uint2*)h;
    *(uint2*)(Y + lo + i * 4) = *(uint2*)l;
}

// ================= MFMA bf16x3 GEMM, pre-split planar inputs =================
// MATH 0: f32 out = alpha*acc + bias[n]; 2: planar gelu(acc+bias); 4: planar acc+bias;
// 5: VQ fused: v = extra[n]-2acc, packed atomicMin into (u64*)Cf per row.
// ksplit>1: raw f32 partials to part.
template<int MATH, bool BKN>
__global__ __launch_bounds__(256)
void gemm_bb(const u16* __restrict__ A, long rsA, long loA, long soA, long siA,
             const u16* __restrict__ B, long rsB, long loB, long soB, long siB,
             const float* __restrict__ bias, long siBias,
             const float* __restrict__ extra,
             float* __restrict__ Cf, int ldc, long soC, long siC,
             u16* __restrict__ Cb, int rsC, long loC,
             float* __restrict__ part, long pstride,
             int M, int N, int K, float alpha,
             int bdiv, int ksplit, int klen)
{
    __shared__ u16 Ah[64 * LP], Al[64 * LP], Bh[64 * LP], Bl[64 * LP];
    const int zb2 = blockIdx.z;
    const int zk = zb2 % ksplit, zb = zb2 / ksplit;
    const int zo = zb / bdiv, zi = zb - zo * bdiv;
    A += zo * soA + zi * siA;
    B += zo * soB + zi * siB;
    const float* bi = bias ? bias + zi * siBias : nullptr;

    const int t = threadIdx.x;
    const int m0 = blockIdx.x << 6, n0 = blockIdx.y << 6;
    const int kbeg = zk * klen;
    int kend = kbeg + klen; if (kend > K) kend = K;

    const int w = t >> 6, lane = t & 63;
    const int wm = w >> 1, wn = w & 1;
    const int l15 = lane & 15, lk = (lane >> 4) << 3;
    const int ar = t >> 2, ac = (t & 3) << 3;
    const int kr = t >> 3, nc = (t & 7) << 3;

    int grA = m0 + ar; if (grA > M - 1) grA = M - 1;
    const u16* Apr = A + (long)grA * rsA;
    int grB = n0 + ar; if (grB > N - 1) grB = N - 1;
    const u16* Bpr = B + (long)grB * rsB;

    f32x4 acc[2][2] = {};

    for (int k0 = kbeg; k0 < kend; k0 += 32) {
        {
            int ka = k0 + ac;
            uint4 vh = {0,0,0,0}, vl = {0,0,0,0};
            if (ka + 8 <= kend) { vh = *(const uint4*)(Apr + ka); vl = *(const uint4*)(Apr + ka + loA); }
            *(uint4*)&Ah[ar * LP + ac] = vh;
            *(uint4*)&Al[ar * LP + ac] = vl;
        }
        if (!BKN) {
            int ka = k0 + ac;
            uint4 vh = {0,0,0,0}, vl = {0,0,0,0};
            if (ka + 8 <= kend) { vh = *(const uint4*)(Bpr + ka); vl = *(const uint4*)(Bpr + ka + loB); }
            *(uint4*)&Bh[ar * LP + ac] = vh;
            *(uint4*)&Bl[ar * LP + ac] = vl;
        } else {
            int kb = k0 + kr;
            uint4 vh = {0,0,0,0}, vl = {0,0,0,0};
            if (kb < kend) {
                const u16* Bp = B + (long)kb * rsB + n0 + nc;
                vh = *(const uint4*)Bp; vl = *(const uint4*)(Bp + loB);
            }
            const u16* ph = (const u16*)&vh; const u16* pl = (const u16*)&vl;
            #pragma unroll
            for (int j = 0; j < 8; ++j) {
                Bh[(nc + j) * LP + kr] = ph[j];
                Bl[(nc + j) * LP + kr] = pl[j];
            }
        }
        __syncthreads();

        bf16x8 ah[2], al2[2], bh2[2], bl2[2];
        #pragma unroll
        for (int mi = 0; mi < 2; ++mi) {
            int row = (wm << 5) + (mi << 4) + l15;
            ah[mi]  = *(const bf16x8*)&Ah[row * LP + lk];
            al2[mi] = *(const bf16x8*)&Al[row * LP + lk];
        }
        #pragma unroll
        for (int ni = 0; ni < 2; ++ni) {
            int row = (wn << 5) + (ni << 4) + l15;
            bh2[ni] = *(const bf16x8*)&Bh[row * LP + lk];
            bl2[ni] = *(const bf16x8*)&Bl[row * LP + lk];
        }
        #pragma unroll
        for (int mi = 0; mi < 2; ++mi)
            #pragma unroll
            for (int ni = 0; ni < 2; ++ni) {
                acc[mi][ni] = __builtin_amdgcn_mfma_f32_16x16x32_bf16(ah[mi],  bh2[ni], acc[mi][ni], 0, 0, 0);
                acc[mi][ni] = __builtin_amdgcn_mfma_f32_16x16x32_bf16(ah[mi],  bl2[ni], acc[mi][ni], 0, 0, 0);
                acc[mi][ni] = __builtin_amdgcn_mfma_f32_16x16x32_bf16(al2[mi], bh2[ni], acc[mi][ni], 0, 0, 0);
            }
        __syncthreads();
    }

    if (ksplit > 1) {
        float* P = part + (long)zk * pstride + zo * soC + zi * siC;
        #pragma unroll
        for (int mi = 0; mi < 2; ++mi)
            #pragma unroll
            for (int ni = 0; ni < 2; ++ni) {
                int gn = n0 + (wn << 5) + (ni << 4) + l15;
                if (gn >= N) continue;
                int gmb = m0 + (wm << 5) + (mi << 4) + ((lane >> 4) << 2);
                #pragma unroll
                for (int r = 0; r < 4; ++r) {
                    int gm = gmb + r;
                    if (gm < M) P[(long)gm * ldc + gn] = acc[mi][ni][r];
                }
            }
        return;
    }
    if (MATH == 0) {
        float* Co = Cf + zo * soC + zi * siC;
        #pragma unroll
        for (int mi = 0; mi < 2; ++mi)
            #pragma unroll
            for (int ni = 0; ni < 2; ++ni) {
                int gn = n0 + (wn << 5) + (ni << 4) + l15;
                if (gn >= N) continue;
                int gmb = m0 + (wm << 5) + (mi << 4) + ((lane >> 4) << 2);
                #pragma unroll
                for (int r = 0; r < 4; ++r) {
                    int gm = gmb + r;
                    if (gm >= M) continue;
                    Co[(long)gm * ldc + gn] = alpha * acc[mi][ni][r] + (bi ? bi[gn] : 0.0f);
                }
            }
    } else if (MATH == 5) {
        u64* mb = (u64*)Cf;
        #pragma unroll
        for (int mi = 0; mi < 2; ++mi) {
            #pragma unroll
            for (int r = 0; r < 4; ++r) {
                u64 best = 0xFFFFFFFFFFFFFFFFULL;
                #pragma unroll
                for (int ni = 0; ni < 2; ++ni) {
                    int gn = n0 + (wn << 5) + (ni << 4) + l15;
                    float v = extra[gn] - 2.0f * acc[mi][ni][r];
                    unsigned ub = __float_as_uint(v);
                    ub = ub ^ ((ub >> 31) ? 0xFFFFFFFFu : 0x80000000u);
                    u64 pk = ((u64)ub << 32) | (unsigned)gn;
                    best = pk < best ? pk : best;
                }
                #pragma unroll
                for (int sft = 1; sft <= 8; sft <<= 1) {
                    u64 o = __shfl_xor(best, sft);
                    best = o < best ? o : best;
                }
                if (l15 == 0) {
                    int gm = m0 + (wm << 5) + (mi << 4) + ((lane >> 4) << 2) + r;
                    if (gm < M) atomicMin(&mb[gm], best);
                }
            }
        }
    } else {
        u16* Cu = Cb + zo * soC + zi * siC;
        #pragma unroll
        for (int mi = 0; mi < 2; ++mi)
            #pragma unroll
            for (int ni = 0; ni < 2; ++ni) {
                int gn = n0 + (wn << 5) + (ni << 4) + l15;
                if (gn >= N) continue;
                int gmb = m0 + (wm << 5) + (mi << 4) + ((lane >> 4) << 2);
                #pragma unroll
                for (int r = 0; r < 4; ++r) {
                    int gm = gmb + r;
                    if (gm >= M) continue;
                    float v = acc[mi][ni][r] + bi[gn];
                    if (MATH == 2) v = gelu_f(v);
                    u16 h, l; split_f32(v, h, l);
                    Cu[(long)gm * rsC + gn] = h;
                    Cu[(long)gm * rsC + gn + loC] = l;
                }
            }
    }
}

// ================= fused flash attention =================
// grid(13 qblocks, 16 b*h), 256 thr. Q in regs, K/V tiles of 32 in LDS,
// online softmax, P via per-wave LDS slice, bf16x3 everywhere.
#define KP 72
#define VP 40
__global__ __launch_bounds__(256)
void flash_kernel(const u16* __restrict__ qkv, u16* __restrict__ atto)
{
    __shared__ u16 Kh[32 * KP], Kl[32 * KP];
    __shared__ u16 Vh[64 * VP], Vl[64 * VP];
    __shared__ u16 Ph[64 * VP], Pl[64 * VP];

    const int qb = blockIdx.x, bh = blockIdx.y;
    const int b = bh >> 3, h = bh & 7;
    const int t = threadIdx.x, w = t >> 6, lane = t & 63;
    const int l15 = lane & 15, g = lane >> 4;
    const long base = (long)b * 784 * 1536;
    const u16* Qg = qkv + base + h * 64;
    const u16* Kg = qkv + base + 512 + h * 64;
    const u16* Vg = qkv + base + 1024 + h * 64;

    const int q0 = qb << 6;
    int qr = q0 + w * 16 + l15; if (qr > 783) qr = 783;
    const u16* Qp = Qg + (long)qr * 1536 + g * 8;
    bf16x8 qh[2], ql[2];
    qh[0] = *(const bf16x8*)(Qp);
    qh[1] = *(const bf16x8*)(Qp + 32);
    ql[0] = *(const bf16x8*)(Qp + QLO);
    ql[1] = *(const bf16x8*)(Qp + QLO + 32);

    f32x4 O[4] = {};
    float m_[4] = {-1e30f, -1e30f, -1e30f, -1e30f};
    float l_[4] = {};

    const int srow = t >> 3, sc = (t & 7) << 3;   // staging map: 32 rows x 8 thr

    for (int j0 = 0; j0 < 784; j0 += 32) {
        // ---- stage K [32 j][64 d] and V^T [64 d][32 j], hi/lo ----
        {
            int jr = j0 + srow;
            if (jr < 784) {
                const u16* Kp = Kg + (long)jr * 1536 + sc;
                *(uint4*)&Kh[srow * KP + sc] = *(const uint4*)(Kp);
                *(uint4*)&Kl[srow * KP + sc] = *(const uint4*)(Kp + QLO);
                const u16* Vp = Vg + (long)jr * 1536 + sc;
                u16 th[8], tl[8];
                *(uint4*)th = *(const uint4*)Vp;
                *(uint4*)tl = *(const uint4*)(Vp + QLO);
                #pragma unroll
                for (int e = 0; e < 8; ++e) {
                    Vh[(sc + e) * VP + srow] = th[e];
                    Vl[(sc + e) * VP + srow] = tl[e];
                }
            } else {
                uint4 zz = {0, 0, 0, 0};
                *(uint4*)&Kh[srow * KP + sc] = zz;
                *(uint4*)&Kl[srow * KP + sc] = zz;
                #pragma unroll
                for (int e = 0; e < 8; ++e) {
                    Vh[(sc + e) * VP + srow] = 0;
                    Vl[(sc + e) * VP + srow] = 0;
                }
            }
        }
        __syncthreads();

        // ---- S = Q K^T ----
        f32x4 S[2] = {};
        #pragma unroll
        for (int f = 0; f < 2; ++f) {
            #pragma unroll
            for (int ks = 0; ks < 2; ++ks) {
                bf16x8 kh = *(const bf16x8*)&Kh[(f * 16 + l15) * KP + ks * 32 + g * 8];
                bf16x8 kl = *(const bf16x8*)&Kl[(f * 16 + l15) * KP + ks * 32 + g * 8];
                S[f] = __builtin_amdgcn_mfma_f32_16x16x32_bf16(qh[ks], kh, S[f], 0, 0, 0);
                S[f] = __builtin_amdgcn_mfma_f32_16x16x32_bf16(qh[ks], kl, S[f], 0, 0, 0);
                S[f] = __builtin_amdgcn_mfma_f32_16x16x32_bf16(ql[ks], kh, S[f], 0, 0, 0);
            }
        }

        // ---- online softmax (rows = g*4+r within wave's 16) ----
        float p[2][4];
        #pragma unroll
        for (int f = 0; f < 2; ++f) {
            bool ok = (j0 + f * 16 + l15) < 784;
            #pragma unroll
            for (int r = 0; r < 4; ++r)
                p[f][r] = ok ? S[f][r] * 0.125f : -1e30f;
        }
        #pragma unroll
        for (int r = 0; r < 4; ++r) {
            float pm = fmaxf(p[0][r], p[1][r]);
            pm = fmaxf(pm, __shfl_xor(pm, 1)); pm = fmaxf(pm, __shfl_xor(pm, 2));
            pm = fmaxf(pm, __shfl_xor(pm, 4)); pm = fmaxf(pm, __shfl_xor(pm, 8));
            float mn = fmaxf(m_[r], pm);
            float scl = expf(m_[r] - mn);
            float rs = 0.f;
            #pragma unroll
            for (int f = 0; f < 2; ++f) { float e = expf(p[f][r] - mn); p[f][r] = e; rs += e; }
            rs += __shfl_xor(rs, 1); rs += __shfl_xor(rs, 2);
            rs += __shfl_xor(rs, 4); rs += __shfl_xor(rs, 8);
            l_[r] = l_[r] * scl + rs;
            m_[r] = mn;
            O[0][r] *= scl; O[1][r] *= scl; O[2][r] *= scl; O[3][r] *= scl;
        }

        // ---- P -> per-wave LDS slice (each wave reads only its own rows) ----
        #pragma unroll
        for (int f = 0; f < 2; ++f)
            #pragma unroll
            for (int r = 0; r < 4; ++r) {
                u16 hh, ll; split_f32(p[f][r], hh, ll);
                int row = w * 16 + g * 4 + r;
                Ph[row * VP + f * 16 + l15] = hh;
                Pl[row * VP + f * 16 + l15] = ll;
            }

        // ---- O += P V ----
        bf16x8 pah = *(const bf16x8*)&Ph[(w * 16 + l15) * VP + g * 8];
        bf16x8 pal = *(const bf16x8*)&Pl[(w * 16 + l15) * VP + g * 8];
        #pragma unroll
        for (int f = 0; f < 4; ++f) {
            bf16x8 vh = *(const bf16x8*)&Vh[(f * 16 + l15) * VP + g * 8];
            bf16x8 vl = *(const bf16x8*)&Vl[(f * 16 + l15) * VP + g * 8];
            O[f] = __builtin_amdgcn_mfma_f32_16x16x32_bf16(pah, vh, O[f], 0, 0, 0);
            O[f] = __builtin_amdgcn_mfma_f32_16x16x32_bf16(pal, vh, O[f], 0, 0, 0);
            O[f] = __builtin_amdgcn_mfma_f32_16x16x32_bf16(pah, vl, O[f], 0, 0, 0);
        }
        __syncthreads();
    }

    // ---- epilogue: O /= l, planar bf16 store ----
    #pragma unroll
    for (int r = 0; r < 4; ++r) {
        int q = q0 + w * 16 + g * 4 + r;
        if (q >= 784) continue;
        long tok = (long)b * 784 + q;
        float inv = 1.0f / l_[r];
        #pragma unroll
        for (int f = 0; f < 4; ++f) {
            float v = O[f][r] * inv;
            u16 hh, ll; split_f32(v, hh, ll);
            long off = tok * 512 + h * 64 + f * 16 + l15;
            atto[off] = hh; atto[off + ALO] = ll;
        }
    }
}

// ================= split-K reduce =================
// 0: Cf=s+b; 1: Cf+=s+b; 2: planar(s+b); 3: Cf=s+b AND planar
template<int MATH>
__global__ __launch_bounds__(256)
void reduce_k(const float* __restrict__ part, long pstride, int ks,
              const float* __restrict__ bias, int ldc,
              float* __restrict__ Cf, u16* __restrict__ Cb, long loC, long total)
{
    long i = (long)blockIdx.x * 256 + threadIdx.x;
    if (i >= total) return;
    float s = 0.f;
    for (int k = 0; k < ks; ++k) s += part[(long)k * pstride + i];
    int col = (int)(i % ldc);
    float b = bias ? bias[col] : 0.0f;
    float v = s + b;
    if (MATH == 0) Cf[i] = v;
    else if (MATH == 1) Cf[i] += v;
    else if (MATH == 2) { u16 h, l; split_f32(v, h, l); Cb[i] = h; Cb[i + loC] = l; }
    else { Cf[i] = v; u16 h, l; split_f32(v, h, l); Cb[i] = h; Cb[i + loC] = l; }
}

// ================= LayerNorm -> planar bf16 =================
__global__ __launch_bounds__(256)
void ln_kernel(const float* __restrict__ x, const float* __restrict__ s,
               const float* __restrict__ b, u16* __restrict__ y, long lo, int rows)
{
    int wave = threadIdx.x >> 6, lane = threadIdx.x & 63;
    int row = (blockIdx.x << 2) + wave;
    if (row >= rows) return;
    const float* xr = x + (long)row * Dq;
    float4 v0 = *(const float4*)(xr + (lane << 2));
    float4 v1 = *(const float4*)(xr + 256 + (lane << 2));
    float sum = v0.x+v0.y+v0.z+v0.w + v1.x+v1.y+v1.z+v1.w;
    sum = wave_sum(sum);
    float m = sum * (1.0f / 512.0f);
    float d0x=v0.x-m,d0y=v0.y-m,d0z=v0.z-m,d0w=v0.w-m;
    float d1x=v1.x-m,d1y=v1.y-m,d1z=v1.z-m,d1w=v1.w-m;
    float vs = d0x*d0x+d0y*d0y+d0z*d0z+d0w*d0w + d1x*d1x+d1y*d1y+d1z*d1z+d1w*d1w;
    vs = wave_sum(vs);
    float rstd = 1.0f / sqrtf(vs * (1.0f / 512.0f) + 1e-6f);
    int c0 = lane << 2;
    u16 h0[4], l0[4], h1[4], l1[4];
    split_f32(d0x*rstd*s[c0+0]+b[c0+0], h0[0], l0[0]);
    split_f32(d0y*rstd*s[c0+1]+b[c0+1], h0[1], l0[1]);
    split_f32(d0z*rstd*s[c0+2]+b[c0+2], h0[2], l0[2]);
    split_f32(d0w*rstd*s[c0+3]+b[c0+3], h0[3], l0[3]);
    split_f32(d1x*rstd*s[256+c0+0]+b[256+c0+0], h1[0], l1[0]);
    split_f32(d1y*rstd*s[256+c0+1]+b[256+c0+1], h1[1], l1[1]);
    split_f32(d1z*rstd*s[256+c0+2]+b[256+c0+2], h1[2], l1[2]);
    split_f32(d1w*rstd*s[256+c0+3]+b[256+c0+3], h1[3], l1[3]);
    u16* yr = y + (long)row * Dq;
    *(uint2*)(yr + c0)            = *(uint2*)h0;
    *(uint2*)(yr + lo + c0)       = *(uint2*)l0;
    *(uint2*)(yr + 256 + c0)      = *(uint2*)h1;
    *(uint2*)(yr + lo + 256 + c0) = *(uint2*)l1;
}

// ================= codebook norms =================
__global__ __launch_bounds__(256)
void cnorm_kernel(const float* __restrict__ cb, float* __restrict__ cn)
{
    int wave = threadIdx.x >> 6, lane = threadIdx.x & 63;
    int row = (blockIdx.x << 2) + wave;
    if (row >= Kq) return;
    const float* cr = cb + (long)row * Dq;
    float4 v0 = *(const float4*)(cr + (lane << 2));
    float4 v1 = *(const float4*)(cr + 256 + (lane << 2));
    float ss = v0.x*v0.x+v0.y*v0.y+v0.z*v0.z+v0.w*v0.w
             + v1.x*v1.x+v1.y*v1.y+v1.z*v1.z+v1.w*v1.w;
    ss = wave_sum(ss);
    if (lane == 0) cn[row] = ss;
}

// ================= patchify / unpatchify / posadd =================
__global__ void patchify_kernel(const float* __restrict__ video, u16* __restrict__ patches)
{
    long i = (long)blockIdx.x * 256 + threadIdx.x;
    if (i >= (long)TOKq * PINq) return;
    int row = (int)(i / PINq), col = (int)(i - (long)row * PINq);
    int c = col % 3; int q = col / 3;
    int pw = q & 15; q >>= 4;
    int ph = q & 15; int tpin = q >> 4;
    int wp = row % 14; int r2 = row / 14;
    int hp = r2 % 14; r2 /= 14;
    int tp = r2 & 3; int b = r2 >> 2;
    int tt = tp * 4 + tpin;
    int ih = hp * 16 + ph, iw = wp * 16 + pw;
    float v = video[(((long)(b * 16 + tt) * 224 + ih) * 224 + iw) * 3 + c];
    u16 h, l; split_f32(v, h, l);
    patches[i] = h; patches[PLO + i] = l;
}

__global__ void unpatchify_kernel(const float* __restrict__ px, float* __restrict__ out)
{
    long o = (long)blockIdx.x * 256 + threadIdx.x;
    if (o >= RECN) return;
    int c = (int)(o % 3); long r = o / 3;
    int iw = (int)(r % 224); r /= 224;
    int ih = (int)(r % 224); r /= 224;
    int tt = (int)(r % 16); int b = (int)(r / 16);
    int tp = tt >> 2, tpin = tt & 3;
    int hp = ih >> 4, ph = ih & 15;
    int wp = iw >> 4, pw = iw & 15;
    long prow = ((long)(b * 4 + tp) * 14 + hp) * 14 + wp;
    int pcol = ((tpin * 16 + ph) * 16 + pw) * 3 + c;
    out[o] = px[prow * PINq + pcol];
}

__global__ void posadd_kernel(float* __restrict__ z, const float* __restrict__ pt,
                              const float* __restrict__ ph, const float* __restrict__ pw)
{
    long i = (long)blockIdx.x * 256 + threadIdx.x;
    if (i >= (long)TOKq * Dq) return;
    int d = (int)(i & 511); long r = i >> 9;
    int w = (int)(r % 14); r /= 14;
    int hh = (int)(r % 14); r /= 14;
    int tp = (int)(r & 3);
    z[i] += pt[tp * Dq + d] + ph[hh * Dq + d] + pw[w * Dq + d];
}

// ================= z_q gather (idx from packed min) + SSE + counts =================
__global__ __launch_bounds__(256)
void zq_kernel(const float* __restrict__ cb, const u64* __restrict__ minb,
               const float* __restrict__ ze, u16* __restrict__ zqp, long lo,
               float* __restrict__ part, float* __restrict__ counts,
               float* __restrict__ out_idx)
{
    int tok = blockIdx.x;
    int id = (int)(minb[tok] & 0xFFFFFFFFULL);
    const float* c = cb + (long)id * Dq;
    const float* z = ze + (long)tok * Dq;
    float ss = 0.f;
    for (int d = threadIdx.x; d < Dq; d += 256) {
        float cv = c[d];
        u16 h, l; split_f32(cv, h, l);
        zqp[(long)tok * Dq + d] = h;
        zqp[lo + (long)tok * Dq + d] = l;
        float df = cv - z[d];
        ss += df * df;
    }
    float wsum = wave_sum(ss);
    __shared__ float sw[4];
    if ((threadIdx.x & 63) == 0) sw[threadIdx.x >> 6] = wsum;
    __syncthreads();
    if (threadIdx.x == 0) {
        part[tok] = sw[0] + sw[1] + sw[2] + sw[3];
        atomicAdd(&counts[id], 1.0f);
        out_idx[tok] = (float)id;
    }
}

// ================= scalars =================
__global__ __launch_bounds__(256)
void scalars_kernel(const float* __restrict__ part, const float* __restrict__ counts,
                    float* __restrict__ out)
{
    float se = 0.f;
    for (int t = threadIdx.x; t < TOKq; t += 256) se += part[t];
    float pl = 0.f;
    for (int k = threadIdx.x; k < Kq; k += 256) {
        float p = counts[k] * (1.0f / 1568.0f);
        pl += p * logf(p + 1e-10f);
    }
    float wse = wave_sum(se), wpl = wave_sum(pl);
    __shared__ float s1[4], s2[4];
    if ((threadIdx.x & 63) == 0) { s1[threadIdx.x >> 6] = wse; s2[threadIdx.x >> 6] = wpl; }
    __syncthreads();
    if (threadIdx.x == 0) {
        float sse = s1[0] + s1[1] + s1[2] + s1[3];
        float plo = s2[0] + s2[1] + s2[2] + s2[3];
        float commit = sse / 802816.0f;
        out[RECN + 1568 + 0] = commit;
        out[RECN + 1568 + 1] = commit;
        out[RECN + 1568 + 2] = expf(-plo);
    }
}

// ================= transformer block =================
static void block_fwd(hipStream_t st, float* z, float* big, float* hbuf,
                      u16* xlnu, u16* qkvu, u16* attou, u16* hbu, u16* wscr,
                      const float* ln1s, const float* ln1b,
                      const float* Wqkv, const float* bqkv,
                      const float* Wo, const float* bo,
                      const float* ln2s, const float* ln2b,
                      const float* W1, const float* b1,
                      const float* W2, const float* b2)
{
    ln_kernel<<<TOKq / 4, 256, 0, st>>>(z, ln1s, ln1b, xlnu, XLO, TOKq);
    wconv_t<<<dim3(16, 16, 3), 256, 0, st>>>(Wqkv, Dq, Dq, wscr, 786432, 262144L, 262144L);
    gemm_bb<4, false><<<dim3(25, 8, 3), 256, 0, st>>>(
        xlnu, Dq, XLO, 0, 0,
        wscr, Dq, 786432, 0, 262144,
        bqkv, 512, nullptr,
        nullptr, 0, 0, 512,
        qkvu, 3 * Dq, QLO,
        nullptr, 0,
        TOKq, Dq, Dq, 1.0f, 3, 1, Dq);
    // fused attention (QK^T + softmax + PV), bf16x3
    flash_kernel<<<dim3(13, 16), 256, 0, st>>>(qkvu, attou);
    // z += atto @ Wo + bo
    wconv_t<<<dim3(16, 16, 1), 256, 0, st>>>(Wo, Dq, Dq, wscr, 262144, 0, 0);
    gemm_bb<0, false><<<dim3(25, 8, 4), 256, 0, st>>>(
        attou, Dq, ALO, 0, 0,
        wscr, Dq, 262144, 0, 0,
        nullptr, 0, nullptr,
        nullptr, Dq, 0, 0,
        nullptr, 0, 0,
        hbuf, CEXT,
        TOKq, Dq, Dq, 1.0f, 1, 4, 128);
    reduce_k<1><<<(CEXT + 255) / 256, 256, 0, st>>>(hbuf, CEXT, 4, bo, Dq, z, nullptr, 0, CEXT);
    // FFN
    ln_kernel<<<TOKq / 4, 256, 0, st>>>(z, ln2s, ln2b, xlnu, XLO, TOKq);
    wconv_t<<<dim3(16, 64, 1), 256, 0, st>>>(W1, DFFq, Dq, wscr, 1048576, 0, 0);
    gemm_bb<2, false><<<dim3(25, 32, 1), 256, 0, st>>>(
        xlnu, Dq, XLO, 0, 0,
        wscr, Dq, 1048576, 0, 0,
        b1, 0, nullptr,
        nullptr, 0, 0, 0,
        hbu, DFFq, HLO,
        nullptr, 0,
        TOKq, DFFq, Dq, 1.0f, 1, 1, Dq);
    wconv_t<<<dim3(64, 16, 1), 256, 0, st>>>(W2, Dq, DFFq, wscr, 1048576, 0, 0);
    gemm_bb<0, false><<<dim3(25, 8, 4), 256, 0, st>>>(
        hbu, DFFq, HLO, 0, 0,
        wscr, DFFq, 1048576, 0, 0,
        nullptr, 0, nullptr,
        nullptr, Dq, 0, 0,
        nullptr, 0, 0,
        big, CEXT,
        TOKq, Dq, DFFq, 1.0f, 1, 4, 512);
    reduce_k<1><<<(CEXT + 255) / 256, 256, 0, st>>>(big, CEXT, 4, b2, Dq, z, nullptr, 0, CEXT);
}

extern "C" void kernel_launch(void* const* d_in, const int* in_sizes, int n_in,
                              void* d_out, int out_size, void* d_ws, size_t ws_size,
                              hipStream_t stream)
{
    (void)in_sizes; (void)n_in; (void)out_size;
    if (ws_size < (size_t)OFF_END * sizeof(float)) return;

    const float* video = (const float*)d_in[0];
    const float* epW   = (const float*)d_in[1];  const float* epb   = (const float*)d_in[2];
    const float* ept   = (const float*)d_in[3];  const float* ephp  = (const float*)d_in[4];
    const float* epwp  = (const float*)d_in[5];
    const float* eln1s = (const float*)d_in[6];  const float* eln1b = (const float*)d_in[7];
    const float* eWqkv = (const float*)d_in[8];  const float* ebqkv = (const float*)d_in[9];
    const float* eWo   = (const float*)d_in[10]; const float* ebo   = (const float*)d_in[11];
    const float* eln2s = (const float*)d_in[12]; const float* eln2b = (const float*)d_in[13];
    const float* eW1   = (const float*)d_in[14]; const float* eb1   = (const float*)d_in[15];
    const float* eW2   = (const float*)d_in[16]; const float* eb2   = (const float*)d_in[17];
    const float* elnfs = (const float*)d_in[18]; const float* elnfb = (const float*)d_in[19];
    const float* ecbW  = (const float*)d_in[20]; const float* ecbb  = (const float*)d_in[21];
    const float* cbook = (const float*)d_in[22];
    const float* dcbW  = (const float*)d_in[23]; const float* dcbb  = (const float*)d_in[24];
    const float* dpt   = (const float*)d_in[25]; const float* dphp  = (const float*)d_in[26];
    const float* dpwp  = (const float*)d_in[27];
    const float* dln1s = (const float*)d_in[28]; const float* dln1b = (const float*)d_in[29];
    const float* dWqkv = (const float*)d_in[30]; const float* dbqkv = (const float*)d_in[31];
    const float* dWo   = (const float*)d_in[32]; const float* dbo   = (const float*)d_in[33];
    const float* dln2s = (const float*)d_in[34]; const float* dln2b = (const float*)d_in[35];
    const float* dW1   = (const float*)d_in[36]; const float* db1   = (const float*)d_in[37];
    const float* dW2   = (const float*)d_in[38]; const float* db2   = (const float*)d_in[39];
    const float* dlnfs = (const float*)d_in[40]; const float* dlnfb = (const float*)d_in[41];
    const float* dpxW  = (const float*)d_in[42]; const float* dpxb  = (const float*)d_in[43];

    float* ws   = (float*)d_ws;
    float* big  = ws + OFF_BIG;
    float* z    = ws + OFF_Z;
    float* xln  = ws + OFF_XLN;
    float* qkv  = ws + OFF_QKV;
    float* atto = ws + OFF_ATTO;
    float* hbuf = ws + OFF_H;
    float* ze   = ws + OFF_ZE;
    float* zq   = ws + OFF_ZQ;
    float* cn   = ws + OFF_CN;
    float* cnt  = ws + OFF_CNT;
    float* part = ws + OFF_PART;
    u64*   minb = (u64*)(ws + OFF_MIN);
    float* out  = (float*)d_out;

    u16* xlnu  = (u16*)xln;
    u16* qkvu  = (u16*)qkv;
    u16* attou = (u16*)atto;
    u16* hbu   = (u16*)hbuf;
    u16* patu  = (u16*)big;
    u16* zqu   = (u16*)zq;
    u16* cbs   = (u16*)qkv;
    u16* wscr  = (u16*)(big + 10485760);

    hipMemsetAsync(cnt, 0, Kq * sizeof(float), stream);
    hipMemsetAsync(minb, 0xFF, TOKq * sizeof(u64), stream);
    cnorm_kernel<<<Kq / 4, 256, 0, stream>>>(cbook, cn);

    // ---- encoder front ----
    patchify_kernel<<<(int)(((long)TOKq * PINq + 255) / 256), 256, 0, stream>>>(video, patu);
    wconv_t<<<dim3(96, 16, 1), 256, 0, stream>>>(epW, Dq, PINq, wscr, 1572864, 0, 0);
    gemm_bb<0, false><<<dim3(25, 8, 6), 256, 0, stream>>>(
        patu, PINq, PLO, 0, 0,
        wscr, PINq, 1572864, 0, 0,
        nullptr, 0, nullptr,
        nullptr, Dq, 0, 0,
        nullptr, 0, 0,
        big + PLO, CEXT,
        TOKq, Dq, PINq, 1.0f, 1, 6, 512);
    reduce_k<0><<<(CEXT + 255) / 256, 256, 0, stream>>>(big + PLO, CEXT, 6, epb, Dq, z, nullptr, 0, CEXT);
    posadd_kernel<<<(int)(((long)TOKq * Dq + 255) / 256), 256, 0, stream>>>(z, ept, ephp, epwp);

    for (int l = 0; l < Lq; ++l)
        block_fwd(stream, z, big, hbuf, xlnu, qkvu, attou, hbu, wscr,
                  eln1s + l * Dq, eln1b + l * Dq,
                  eWqkv + (long)l * 3 * Dq * Dq, ebqkv + l * 3 * Dq,
                  eWo + (long)l * Dq * Dq, ebo + l * Dq,
                  eln2s + l * Dq, eln2b + l * Dq,
                  eW1 + (long)l * Dq * DFFq, eb1 + l * DFFq,
                  eW2 + (long)l * DFFq * Dq, eb2 + l * Dq);

    // ---- encoder head ----
    ln_kernel<<<TOKq / 4, 256, 0, stream>>>(z, elnfs, elnfb, xlnu, XLO, TOKq);
    wconv_t<<<dim3(16, 16, 1), 256, 0, stream>>>(ecbW, Dq, Dq, wscr, 262144, 0, 0);
    gemm_bb<0, false><<<dim3(25, 8, 2), 256, 0, stream>>>(
        xlnu, Dq, XLO, 0, 0,
        wscr, Dq, 262144, 0, 0,
        nullptr, 0, nullptr,
        nullptr, Dq, 0, 0,
        nullptr, 0, 0,
        big, CEXT,
        TOKq, Dq, Dq, 1.0f, 1, 2, 256);
    reduce_k<3><<<(CEXT + 255) / 256, 256, 0, stream>>>(big, CEXT, 2, ecbb, Dq, ze, zqu, ZLO, CEXT);

    // ---- VQ: fused d2 + argmin (packed atomicMin) ----
    splitp<<<(int)(((long)Kq * Dq / 4 + 255) / 256), 256, 0, stream>>>(cbook, cbs, CBLO, (long)Kq * Dq / 4);
    gemm_bb<5, false><<<dim3(25, 128, 1), 256, 0, stream>>>(
        zqu, Dq, ZLO, 0, 0,
        cbs, Dq, CBLO, 0, 0,
        nullptr, 0, cn,
        (float*)minb, Kq, 0, 0,
        nullptr, 0, 0,
        nullptr, 0,
        TOKq, Kq, Dq, 1.0f, 1, 1, Dq);
    zq_kernel<<<TOKq, 256, 0, stream>>>(cbook, minb, ze, zqu, ZLO, part, cnt, out + RECN);
    scalars_kernel<<<1, 256, 0, stream>>>(part, cnt, out);

    // ---- decoder front ----
    wconv_t<<<dim3(16, 16, 1), 256, 0, stream>>>(dcbW, Dq, Dq, wscr, 262144, 0, 0);
    gemm_bb<0, false><<<dim3(25, 8, 2), 256, 0, stream>>>(
        zqu, Dq, ZLO, 0, 0,
        wscr, Dq, 262144, 0, 0,
        nullptr, 0, nullptr,
        nullptr, Dq, 0, 0,
        nullptr, 0, 0,
        big, CEXT,
        TOKq, Dq, Dq, 1.0f, 1, 2, 256);
    reduce_k<0><<<(CEXT + 255) / 256, 256, 0, stream>>>(big, CEXT, 2, dcbb, Dq, z, nullptr, 0, CEXT);
    posadd_kernel<<<(int)(((long)TOKq * Dq + 255) / 256), 256, 0, stream>>>(z, dpt, dphp, dpwp);

    for (int l = 0; l < Lq; ++l)
        block_fwd(stream, z, big, hbuf, xlnu, qkvu, attou, hbu, wscr,
                  dln1s + l * Dq, dln1b + l * Dq,
                  dWqkv + (long)l * 3 * Dq * Dq, dbqkv + l * 3 * Dq,
                  dWo + (long)l * Dq * Dq, dbo + l * Dq,
                  dln2s + l * Dq, dln2b + l * Dq,
                  dW1 + (long)l * Dq * DFFq, db1 + l * DFFq,
                  dW2 + (long)l * DFFq * Dq, db2 + l * Dq);

    // ---- decoder head ----
    ln_kernel<<<TOKq / 4, 256, 0, stream>>>(z, dlnfs, dlnfb, xlnu, XLO, TOKq);
    wconv_t<<<dim3(16, 96, 1), 256, 0, stream>>>(dpxW, PINq, Dq, wscr, 1572864, 0, 0);
    gemm_bb<0, false><<<dim3(25, 48, 1), 256, 0, stream>>>(
        xlnu, Dq, XLO, 0, 0,
        wscr, Dq, 1572864, 0, 0,
        dpxb, 0, nullptr,
        big, PINq, 0, 0,
        nullptr, 0, 0,
        nullptr, 0,
        TOKq, PINq, Dq, 1.0f, 1, 1, Dq);
    unpatchify_kernel<<<(int)((RECN + 255) / 256), 256, 0, stream>>>(big, out);
}